// Round 11
// baseline (1719.576 us; speedup 1.0000x reference)
//
#include <hip/hip_runtime.h>

typedef unsigned short u16;
typedef unsigned int u32;
typedef __attribute__((ext_vector_type(8))) short short8;
typedef __attribute__((ext_vector_type(8))) unsigned short ushort8v;
typedef __attribute__((ext_vector_type(4))) float f32x4;

#define CDIM 128

__device__ __forceinline__ float b2f(u16 u){ return __uint_as_float(((unsigned)u)<<16); }
__device__ __forceinline__ u16 f2b(float f){
  unsigned x = __float_as_uint(f);
  unsigned r = (x + 0x7fffu + ((x>>16)&1u)) >> 16;
  return (u16)r;
}
__device__ __forceinline__ float wsum64(float v){
  #pragma unroll
  for(int d=1; d<64; d<<=1) v += __shfl_xor(v, d, 64);
  return v;
}
__device__ __forceinline__ float wsum16(float v){
  v += __shfl_xor(v, 1, 64);
  v += __shfl_xor(v, 2, 64);
  v += __shfl_xor(v, 4, 64);
  v += __shfl_xor(v, 8, 64);
  return v;
}

// ---------------- dtype probe ----------------
__global__ void k_probe(const u32* __restrict__ x, const u32* __restrict__ ei, int* __restrict__ flags){
  __shared__ int s_bf, s_nz;
  if(threadIdx.x == 0){ s_bf = 0; s_nz = 0; }
  __syncthreads();
  int c_bf = 0, c_nz = 0;
  for(int i = threadIdx.x; i < 4096; i += 256){
    u32 w = x[i];
    u32 e = (w >> 7) & 0xFFu;
    if(e >= 100u && e <= 140u) c_bf++;
    if(ei[2*i + 1] != 0u) c_nz++;
  }
  atomicAdd(&s_bf, c_bf);
  atomicAdd(&s_nz, c_nz);
  __syncthreads();
  if(threadIdx.x == 0){
    flags[0] = (s_bf < 2048) ? 1 : 0;
    flags[1] = (s_nz < 8) ? 1 : 0;
  }
}

// ---------------- conversions ----------------
__global__ void k_cvt_x(const void* __restrict__ src, u16* __restrict__ dst, int n,
                        const int* __restrict__ flags){
  int i = (blockIdx.x*256 + threadIdx.x)*8;
  if(i + 7 >= n) return;
  if(flags[0]){
    const float* s = (const float*)src + i;
    float4 a = *(const float4*)s;
    float4 b = *(const float4*)(s + 4);
    ushort8v o;
    o[0]=f2b(a.x); o[1]=f2b(a.y); o[2]=f2b(a.z); o[3]=f2b(a.w);
    o[4]=f2b(b.x); o[5]=f2b(b.y); o[6]=f2b(b.z); o[7]=f2b(b.w);
    *(ushort8v*)(dst + i) = o;
  } else {
    *(ushort8v*)(dst + i) = *(const ushort8v*)((const u16*)src + i);
  }
}

struct CvtArgs {
  const void* src[24];
  u16* dst[24];
  int n[24];
};

__global__ void k_cvt_params(CvtArgs a, const int* __restrict__ flags){
  int seg = blockIdx.y;
  int i = blockIdx.x*256 + threadIdx.x;
  int n = a.n[seg];
  if(i >= n) return;
  if(flags[0]) a.dst[seg][i] = f2b(((const float*)a.src[seg])[i]);
  else         a.dst[seg][i] = ((const u16*)a.src[seg])[i];
}

// convert edge index (int64->int32 if needed) + count destination degrees in the same pass
__global__ void k_cvt_ei_count(const int* __restrict__ src, int* __restrict__ dst, int E,
                               const int* __restrict__ flags, u32* __restrict__ cnt){
  int i = blockIdx.x*256 + threadIdx.x;
  if(i >= 2*E) return;
  int v = flags[1] ? src[2*i] : src[i];
  dst[i] = v;
  if(i >= E) atomicAdd(&cnt[v], 1u);
}

// ---------------- multi-block exclusive scan of cnt -> rowstart (+cursor, dinv) ----------------
__global__ __launch_bounds__(256) void k_scan1(const u32* __restrict__ cnt, int n, u32* __restrict__ bsum){
  const int lane = threadIdx.x & 63;
  const int wv = threadIdx.x >> 6;
  int i = blockIdx.x*256 + threadIdx.x;
  u32 v = (i < n) ? cnt[i] : 0u;
  #pragma unroll
  for(int d=1; d<64; d<<=1) v += (u32)__shfl_xor((int)v, d, 64);
  __shared__ u32 ws[4];
  if(lane == 0) ws[wv] = v;
  __syncthreads();
  if(threadIdx.x == 0) bsum[blockIdx.x] = ws[0] + ws[1] + ws[2] + ws[3];
}

__global__ __launch_bounds__(1024) void k_scan2(const u32* __restrict__ bsum, int nb, u32* __restrict__ bpre){
  __shared__ u32 s[1024];
  int t = threadIdx.x;
  u32 v = (t < nb) ? bsum[t] : 0u;
  s[t] = v;
  __syncthreads();
  for(int d=1; d<1024; d<<=1){
    u32 y = (t >= d) ? s[t-d] : 0u;
    __syncthreads();
    s[t] += y;
    __syncthreads();
  }
  if(t < nb) bpre[t] = s[t] - v;   // exclusive
}

__global__ __launch_bounds__(256) void k_scan3(const u32* __restrict__ cnt, int n,
                                               const u32* __restrict__ bpre,
                                               u32* __restrict__ rowstart, u32* __restrict__ cursor,
                                               float* __restrict__ dinv){
  const int lane = threadIdx.x & 63;
  const int wv = threadIdx.x >> 6;
  int i = blockIdx.x*256 + threadIdx.x;
  u32 v = (i < n) ? cnt[i] : 0u;
  u32 x = v;
  #pragma unroll
  for(int d=1; d<64; d<<=1){
    u32 y = (u32)__shfl_up((int)x, d, 64);
    if(lane >= d) x += y;
  }
  __shared__ u32 ws[4];
  if(lane == 63) ws[wv] = x;
  __syncthreads();
  u32 woff = 0;
  #pragma unroll
  for(int w=0; w<4; w++) if(w < wv) woff += ws[w];
  u32 incl = x + woff;
  u32 rs = bpre[blockIdx.x] + incl - v;
  if(i < n){
    rowstart[i] = rs;
    cursor[i] = rs;
    dinv[i] = rsqrtf((float)(v + 1u));
    if(i == n-1) rowstart[n] = rs + v;
  }
}

// ---------------- dst-range-partitioned scatter ----------------
__global__ __launch_bounds__(256) void k_scatter8(
  const int* __restrict__ ei, int E, int Nn, int nsl,
  u32* __restrict__ cursor, const float* __restrict__ dinv, int2* __restrict__ colw)
{
  const int r = blockIdx.x & 7;
  const int slice = blockIdx.x >> 3;
  const int q = (Nn + 7) >> 3;
  const int lo = r*q;
  const int hi = (lo + q < Nn) ? lo + q : Nn;
  const int chunk = (E + nsl - 1) / nsl;
  int e0 = slice*chunk;
  int e1 = e0 + chunk; if(e1 > E) e1 = E;
  for(int e = e0 + threadIdx.x; e < e1; e += 256){
    int d = ei[E + e];
    if(d >= lo && d < hi){
      int s = ei[e];
      u32 p = atomicAdd(&cursor[d], 1u);
      colw[p] = make_int2(s, __float_as_int(dinv[s]));
    }
  }
}

// ---------------- fused GEMM, transposed MFMA + wave-private LDS transpose for stores ----------------
// acc (4ch x 1node per lane) -> bf16 LDS tile (stride 136 u16, 16B-aligned rows, wave-private,
// no syncthreads) -> b128 reads + dwordx4 stores: 16 lines/instr instead of 64 (8x fewer L2
// store requests — r7/r8 evidence: gemm3 is L2-request-bound, all pipes <11%).
__global__ __launch_bounds__(256) void k_gemm3(
  const u16* __restrict__ A, int M,
  const u16* __restrict__ W0, const u16* __restrict__ bs0, int op0, u16* __restrict__ O0,
  const u16* __restrict__ W1, const u16* __restrict__ bs1, int op1, u16* __restrict__ O1,
  const u16* __restrict__ W2, const u16* __restrict__ bs2, int op2, u16* __restrict__ O2)
{
  __shared__ u16 stg[4][32*136];
  const int lane = threadIdx.x & 63;
  const int wv = threadIdx.x >> 6;
  const int l16 = lane & 15, quad = lane >> 4;
  const long nbase = (long)blockIdx.x*128 + wv*32;

  const u16* Ws[3] = {W0, W1, W2};
  const u16* Bs[3] = {bs0, bs1, bs2};
  u16* Os[3] = {O0, O1, O2};
  const int ops[3] = {op0, op1, op2};
  const int w = blockIdx.y;
  const u16* Wm = Ws[w];
  const int op = ops[w];
  u16* Op = Os[w];
  const u16* bp = Bs[w];
  u16* st = stg[wv];

  short8 xf[2][4];             // B-operand: node nbase+nt*16+l16, k = quad*8 + kt*32
  #pragma unroll
  for(int nt=0; nt<2; nt++){
    long r = nbase + nt*16 + l16; if(r >= M) r = M-1;
    const u16* ap = A + r*CDIM + quad*8;
    #pragma unroll
    for(int kt=0; kt<4; kt++)
      xf[nt][kt] = *(const short8*)(ap + kt*32);
  }

  #pragma unroll
  for(int ct=0; ct<8; ct++){
    f32x4 acc0 = {0.f,0.f,0.f,0.f}, acc1 = {0.f,0.f,0.f,0.f};
    const u16* wp = Wm + (ct*16 + l16)*CDIM + quad*8;   // A-operand: ch ct*16+l16, k quad*8+j
    #pragma unroll
    for(int kt=0; kt<4; kt++){
      short8 wf = *(const short8*)(wp + kt*32);
      acc0 = __builtin_amdgcn_mfma_f32_16x16x32_bf16(wf, xf[0][kt], acc0, 0, 0, 0);
      acc1 = __builtin_amdgcn_mfma_f32_16x16x32_bf16(wf, xf[1][kt], acc1, 0, 0, 0);
    }
    float bv[4] = {0.f,0.f,0.f,0.f};
    if(bp){
      ushort4 bq = *(const ushort4*)(bp + ct*16 + quad*4);
      bv[0]=b2f(bq.x); bv[1]=b2f(bq.y); bv[2]=b2f(bq.z); bv[3]=b2f(bq.w);
    }
    #pragma unroll
    for(int nt=0; nt<2; nt++){
      f32x4 a = nt ? acc1 : acc0;
      u16 o[4];
      #pragma unroll
      for(int g=0; g<4; g++){
        float v = a[g] + bv[g];
        if(op == 1) v = fmaxf(v, 0.f);
        else if(op == 2) v = 1.f/(1.f + __expf(-v));
        o[g] = f2b(v);
      }
      u32 p0 = (u32)o[0] | ((u32)o[1] << 16);
      u32 p1 = (u32)o[2] | ((u32)o[3] << 16);
      *(uint2*)&st[(nt*16 + l16)*136 + ct*16 + quad*4] = make_uint2(p0, p1);
    }
  }
  // copy-out: 8 instrs, each 64 lanes x 16B covering 16 rows (4 lanes per 64B line)
  #pragma unroll
  for(int p2=0; p2<8; p2++){
    int row = (p2>>2)*16 + (lane>>2);
    int seg = (lane&3) + (p2&3)*4;
    long node = nbase + row;
    ushort8v v = *(const ushort8v*)&st[row*136 + seg*8];
    if(node < M)
      *(ushort8v*)(Op + (size_t)node*CDIM + seg*8) = v;
  }
}

// ---------------- per-layer: quad-per-edge gather + LDS redistribute + 2ch/lane epilogue ----------------
__global__ __launch_bounds__(256) void k_layer_epi(
  const u16* __restrict__ xw, const u16* __restrict__ h, const u16* __restrict__ xl,
  const int2* __restrict__ colw, const u32* __restrict__ rowstart, const float* __restrict__ dinv,
  const u16* __restrict__ bg, const u16* __restrict__ bng, const u16* __restrict__ bnb,
  const u16* __restrict__ bnrm, const u16* __restrict__ bnrv,
  const u16* __restrict__ lng, const u16* __restrict__ lnb,
  const u16* __restrict__ flng, const u16* __restrict__ flnb,
  float* __restrict__ xlocal, u16* __restrict__ xout, int n, int first, int final)
{
  __shared__ float redis[4][128];
  const int lane = threadIdx.x & 63;
  const int quad = lane >> 4;
  const int l16 = lane & 15;
  const int wv = threadIdx.x >> 6;
  int node = blockIdx.x*4 + wv;
  const int valid = (node < n);
  if(!valid) node = n - 1;
  const int cg = l16*8;
  u32 j0 = rowstart[node], j1 = rowstart[node+1];
  float a[8];
  #pragma unroll
  for(int g=0; g<8; g++) a[g] = 0.f;

  for(u32 base = j0; base < j1; base += 64){
    int avail = (int)(j1 - base);
    int cnt = avail < 64 ? avail : 64;
    int2 pw = make_int2(0, 0);              // pad: src 0 (valid row), w = +0.0f
    if(lane < cnt) pw = colw[base + lane];
    int cntp = (cnt + 15) & ~15;
    for(int t = 0; t < cntp; t += 16){
      int s[4]; float w[4]; ushort8v v[4];
      #pragma unroll
      for(int u=0; u<4; u++){
        s[u] = __shfl(pw.x, t + u*4 + quad, 64);
        w[u] = __int_as_float(__shfl(pw.y, t + u*4 + quad, 64));
      }
      #pragma unroll
      for(int u=0; u<4; u++) v[u] = *(const ushort8v*)(xw + (size_t)s[u]*CDIM + cg);
      #pragma unroll
      for(int u=0; u<4; u++){
        #pragma unroll
        for(int g=0; g<8; g++) a[g] = fmaf(w[u], b2f(v[u][g]), a[g]);
      }
    }
  }
  #pragma unroll
  for(int g=0; g<8; g++){
    a[g] += __shfl_xor(a[g], 16, 64);
    a[g] += __shfl_xor(a[g], 32, 64);
  }
  if(quad == 0){
    *(float4*)&redis[wv][cg]     = make_float4(a[0],a[1],a[2],a[3]);
    *(float4*)&redis[wv][cg + 4] = make_float4(a[4],a[5],a[6],a[7]);
  }
  __syncthreads();
  const int c0 = lane*2;
  float2 av = *(float2*)&redis[wv][c0];
  float a0 = av.x, a1 = av.y;

  float dn = dinv[node], sw = dn*dn;
  size_t base = (size_t)node*CDIM + c0;
  ushort2 xwv = *(const ushort2*)(xw + base);
  ushort2 xlv = *(const ushort2*)(xl + base);
  ushort2 hv  = *(const ushort2*)(h  + base);
  float x10 = a0*dn + b2f(xwv.x)*sw + b2f(bg[c0])   + b2f(xlv.x);
  float x11 = a1*dn + b2f(xwv.y)*sw + b2f(bg[c0+1]) + b2f(xlv.y);
  float s0 = rsqrtf(b2f(bnrv[c0])   + 1e-5f) * b2f(bng[c0]);
  float s1 = rsqrtf(b2f(bnrv[c0+1]) + 1e-5f) * b2f(bng[c0+1]);
  float x20 = (x10 - b2f(bnrm[c0]))*s0   + b2f(bnb[c0]);
  float x21 = (x11 - b2f(bnrm[c0+1]))*s1 + b2f(bnb[c0+1]);
  float x30 = fmaxf(x20, 0.f);
  float x31 = fmaxf(x21, 0.f);
  float t0 = b2f(hv.x)*x30, t1 = b2f(hv.y)*x31;
  float mu = wsum64(t0 + t1) * (1.f/128.f);
  float d0 = t0 - mu, d1 = t1 - mu;
  float var = wsum64(d0*d0 + d1*d1) * (1.f/128.f);
  float inv = rsqrtf(var + 1e-5f);
  float y0 = d0*inv*b2f(lng[c0])   + b2f(lnb[c0]);
  float y1 = d1*inv*b2f(lng[c0+1]) + b2f(lnb[c0+1]);
  float xn0 = 0.1f*y0 + 0.9f*x30;
  float xn1 = 0.1f*y1 + 0.9f*x31;
  float2 xl2;
  if(first){
    xl2.x = xn0; xl2.y = xn1;
  } else {
    xl2 = *(float2*)(xlocal + base);
    xl2.x += xn0; xl2.y += xn1;
  }
  if(!final){
    if(valid){
      *(float2*)(xlocal + base) = xl2;
      ushort2 o; o.x = f2b(xn0); o.y = f2b(xn1);
      *(ushort2*)(xout + base) = o;
    }
  } else {
    float mu2 = wsum64(xl2.x + xl2.y) * (1.f/128.f);
    float e0 = xl2.x - mu2, e1 = xl2.y - mu2;
    float var2 = wsum64(e0*e0 + e1*e1) * (1.f/128.f);
    float inv2 = rsqrtf(var2 + 1e-5f);
    if(valid){
      ushort2 o;
      o.x = f2b(e0*inv2*b2f(flng[c0])   + b2f(flnb[c0]));
      o.y = f2b(e1*inv2*b2f(flng[c0+1]) + b2f(flnb[c0+1]));
      *(ushort2*)(xout + base) = o;
    }
  }
}

// ---------------- kv = k^T v partials (+ k column sums) ----------------
__global__ __launch_bounds__(256) void k_kv(
  const u16* __restrict__ kk, const u16* __restrict__ vv, int n, int npb,
  float* __restrict__ part)
{
  __shared__ float sk[8][128];
  __shared__ float sv[8][128];
  const int tid = threadIdx.x;
  const int tr = tid >> 4, tc = tid & 15;
  float acc[8][8];
  #pragma unroll
  for(int i=0;i<8;i++){
    #pragma unroll
    for(int j=0;j<8;j++) acc[i][j] = 0.f;
  }
  float ks[8];
  #pragma unroll
  for(int i=0;i<8;i++) ks[i] = 0.f;
  int start = blockIdx.x * npb;
  int end = start + npb; if(end > n) end = n;
  const int lr = tid >> 5;
  const int lc = (tid & 31) * 4;
  for(int g0 = start; g0 < end; g0 += 8){
    int cnt = end - g0; if(cnt > 8) cnt = 8;
    __syncthreads();
    if(lr < cnt){
      ushort4 kq = *(const ushort4*)(kk + (size_t)(g0+lr)*CDIM + lc);
      ushort4 vq = *(const ushort4*)(vv + (size_t)(g0+lr)*CDIM + lc);
      sk[lr][lc] = b2f(kq.x); sk[lr][lc+1] = b2f(kq.y); sk[lr][lc+2] = b2f(kq.z); sk[lr][lc+3] = b2f(kq.w);
      sv[lr][lc] = b2f(vq.x); sv[lr][lc+1] = b2f(vq.y); sv[lr][lc+2] = b2f(vq.z); sv[lr][lc+3] = b2f(vq.w);
    }
    __syncthreads();
    for(int r=0; r<cnt; r++){
      float4 ka = *(const float4*)&sk[r][tr*8];
      float4 kb = *(const float4*)&sk[r][tr*8+4];
      float4 va = *(const float4*)&sv[r][tc*8];
      float4 vb = *(const float4*)&sv[r][tc*8+4];
      float kr[8] = {ka.x,ka.y,ka.z,ka.w,kb.x,kb.y,kb.z,kb.w};
      float vr[8] = {va.x,va.y,va.z,va.w,vb.x,vb.y,vb.z,vb.w};
      #pragma unroll
      for(int i=0;i<8;i++){
        #pragma unroll
        for(int j=0;j<8;j++) acc[i][j] = fmaf(kr[i], vr[j], acc[i][j]);
      }
      if(tc == 0){
        #pragma unroll
        for(int i=0;i<8;i++) ks[i] += kr[i];
      }
    }
  }
  float* p = part + (size_t)blockIdx.x * 16512;
  #pragma unroll
  for(int i=0;i<8;i++){
    #pragma unroll
    for(int j=0;j<8;j++)
      p[(size_t)(tc*8+j)*CDIM + tr*8 + i] = acc[i][j];
  }
  if(tc == 0){
    #pragma unroll
    for(int i=0;i<8;i++) p[16384 + tr*8 + i] = ks[i];
  }
}

// reduce partials -> Bext bf16 [144][128]
__global__ void k_kvred(const float* __restrict__ part, int nb, u16* __restrict__ Bext){
  int i = blockIdx.x*256 + threadIdx.x;
  if(i >= 144*128) return;
  float s = 0.f;
  if(i < 16512){
    #pragma unroll 8
    for(int b=0;b<nb;b++) s += part[(size_t)b*16512 + i];
  }
  Bext[i] = f2b(s);
}

// ---------------- num GEMM + den + LN epilogue + LDS-staged coalesced output (x (h+beta) fused at copy-out) ----------------
__global__ __launch_bounds__(256) void k_attn(
  const u16* __restrict__ q, const u16* __restrict__ Bext, const u16* __restrict__ hg,
  const u16* __restrict__ g, const u16* __restrict__ b,
  u16* __restrict__ out, int M)
{
  __shared__ u16 stg[4][32*136];
  const int lane = threadIdx.x & 63;
  const int wv = threadIdx.x >> 6;
  const int l16 = lane & 15, quad = lane >> 4;
  const long rbase = (long)blockIdx.x*128 + wv*32;
  u16* st = stg[wv];

  short8 af[2][4];
  #pragma unroll
  for(int rt=0; rt<2; rt++){
    long r = rbase + rt*16 + l16; if(r >= M) r = M-1;
    const u16* ap = q + r*CDIM + quad*8;
    #pragma unroll
    for(int kt=0; kt<4; kt++)
      af[rt][kt] = *(const short8*)(ap + kt*32);
  }
  f32x4 acc[2][9];
  f32x4 zero = {0.f,0.f,0.f,0.f};
  #pragma unroll
  for(int rt=0; rt<2; rt++){
    #pragma unroll
    for(int ct=0; ct<9; ct++) acc[rt][ct] = zero;
  }
  #pragma unroll
  for(int ct=0; ct<9; ct++){
    const u16* wp = Bext + (ct*16 + l16)*CDIM + quad*8;
    #pragma unroll
    for(int kt=0; kt<4; kt++){
      short8 bf = *(const short8*)(wp + kt*32);
      acc[0][ct] = __builtin_amdgcn_mfma_f32_16x16x32_bf16(af[0][kt], bf, acc[0][ct], 0, 0, 0);
      acc[1][ct] = __builtin_amdgcn_mfma_f32_16x16x32_bf16(af[1][kt], bf, acc[1][ct], 0, 0, 0);
    }
  }
  #pragma unroll
  for(int rt=0; rt<2; rt++){
    float rden[4];
    #pragma unroll
    for(int gi=0; gi<4; gi++){
      float dv = __shfl(acc[rt][8][gi], lane & 48, 64);
      rden[gi] = 1.f/(dv + 1e-6f);
    }
    #pragma unroll
    for(int gi=0; gi<4; gi++){
      float sum = 0.f;
      #pragma unroll
      for(int ct=0; ct<8; ct++) sum += acc[rt][ct][gi]*rden[gi];
      float mu = wsum16(sum) * (1.f/128.f);
      float vs = 0.f;
      #pragma unroll
      for(int ct=0; ct<8; ct++){ float d = acc[rt][ct][gi]*rden[gi] - mu; vs = fmaf(d, d, vs); }
      float inv = rsqrtf(wsum16(vs)*(1.f/128.f) + 1e-5f);
      const int rowl = rt*16 + quad*4 + gi;
      #pragma unroll
      for(int ct=0; ct<8; ct++){
        int col = ct*16 + l16;
        float y = (acc[rt][ct][gi]*rden[gi] - mu)*inv*b2f(g[col]) + b2f(b[col]);
        st[rowl*136 + col] = f2b(y);
      }
    }
  }
  // copy-out with coalesced hg fusion: 8 instrs, 16 lines each
  #pragma unroll
  for(int p2=0; p2<8; p2++){
    int row = (p2>>2)*16 + (lane>>2);
    int seg = (lane&3) + (p2&3)*4;
    long node = rbase + row;
    if(node >= M) node = M-1;
    ushort8v yv = *(const ushort8v*)&st[row*136 + seg*8];
    ushort8v hv = *(const ushort8v*)(hg + (size_t)node*CDIM + seg*8);
    ushort8v o;
    #pragma unroll
    for(int i2=0; i2<8; i2++)
      o[i2] = f2b(b2f(yv[i2]) * (b2f(hv[i2]) + 0.9f));
    if(rbase + row < M)
      *(ushort8v*)(out + (size_t)node*CDIM + seg*8) = o;
  }
}

// ---------------- final projection: out[N,40] = A @ Wp^T + bp ----------------
__global__ __launch_bounds__(256) void k_gout(
  const u16* __restrict__ A, const u16* __restrict__ W, const u16* __restrict__ bs,
  void* __restrict__ outv, int M, const int* __restrict__ flags)
{
  const int lane = threadIdx.x & 63;
  const int wv = threadIdx.x >> 6;
  const int l16 = lane & 15, quad = lane >> 4;
  const long rbase = (long)blockIdx.x*128 + wv*32;
  const int f32m = flags[0];
  short8 af[2][4];
  #pragma unroll
  for(int rt=0; rt<2; rt++){
    long r = rbase + rt*16 + l16; if(r >= M) r = M-1;
    const u16* ap = A + r*CDIM + quad*8;
    #pragma unroll
    for(int kt=0; kt<4; kt++)
      af[rt][kt] = *(const short8*)(ap + kt*32);
  }
  f32x4 acc[2][3];
  f32x4 zero = {0.f,0.f,0.f,0.f};
  #pragma unroll
  for(int rt=0; rt<2; rt++){
    #pragma unroll
    for(int ct=0; ct<3; ct++) acc[rt][ct] = zero;
  }
  #pragma unroll
  for(int ct=0; ct<3; ct++){
    int row = ct*16 + l16; if(row > 39) row = 39;
    const u16* wp = W + row*CDIM + quad*8;
    #pragma unroll
    for(int kt=0; kt<4; kt++){
      short8 bf = *(const short8*)(wp + kt*32);
      acc[0][ct] = __builtin_amdgcn_mfma_f32_16x16x32_bf16(af[0][kt], bf, acc[0][ct], 0, 0, 0);
      acc[1][ct] = __builtin_amdgcn_mfma_f32_16x16x32_bf16(af[1][kt], bf, acc[1][ct], 0, 0, 0);
    }
  }
  #pragma unroll
  for(int ct=0; ct<3; ct++){
    int col = ct*16 + l16;
    if(col < 40){
      float bias = b2f(bs[col]);
      #pragma unroll
      for(int rt=0; rt<2; rt++){
        #pragma unroll
        for(int gi=0; gi<4; gi++){
          long r = rbase + rt*16 + quad*4 + gi;
          if(r < M){
            float v = acc[rt][ct][gi] + bias;
            if(f32m) ((float*)outv)[r*40 + col] = v;
            else     ((u16*)outv)[r*40 + col] = f2b(v);
          }
        }
      }
    }
  }
}

extern "C" void kernel_launch(void* const* d_in, const int* in_sizes, int n_in,
                              void* d_out, int out_size, void* d_ws, size_t ws_size,
                              hipStream_t stream)
{
  (void)n_in;
  const int C = CDIM;
  const int Nn = in_sizes[0] / C;
  const int E  = in_sizes[1] / 2;

  char* ws = (char*)d_ws;
  size_t off = 0;
  auto alloc = [&](size_t bytes) -> char* {
    char* p = ws + off;
    off = (off + bytes + 255) & ~(size_t)255;
    return p;
  };
  u16*   x_cur  = (u16*)  alloc((size_t)Nn*C*2);     // also xg after final epi
  float* xlocal = (float*)alloc((size_t)Nn*C*4);     // early: [xb bf16 | eib]; then accum; then kvpart
  u16*   hb     = (u16*)  alloc((size_t)Nn*C*2);
  u16*   xwb    = (u16*)  alloc((size_t)Nn*C*2);
  u16*   xlb    = (u16*)  alloc((size_t)Nn*C*2);
  float* dinv   = (float*)alloc((size_t)Nn*4);
  u32*   cnt    = (u32*)  alloc((size_t)Nn*4);
  u32*   rowst  = (u32*)  alloc((size_t)(Nn+1)*4);
  u32*   cursor = (u32*)  alloc((size_t)Nn*4);
  int2*  colw   = (int2*) alloc((size_t)E*8);
  u16*   Bext   = (u16*)  alloc((size_t)144*128*2);
  int*   flags  = (int*)  alloc(256);
  u32*   bsum   = (u32*)  alloc(1024*4);
  u32*   bpre   = (u32*)  alloc(1024*4);
  size_t ptot = 0;
  for(int k=2;k<26;k++) ptot += (size_t)in_sizes[k];
  u16* pbuf = (u16*)alloc(ptot*2);

  if(off > ws_size){
    hipMemsetAsync(d_out, 0, (size_t)out_size*2, stream);
    return;
  }

  const u16* pp[26];
  {
    size_t po = 0;
    for(int k=2;k<26;k++){ pp[k] = pbuf + po; po += (size_t)in_sizes[k]; }
  }
  const u16* cWh  = pp[2];  const u16* cbh  = pp[3];
  const u16* cWg  = pp[4];  const u16* cbg  = pp[5];
  const u16* cWl  = pp[6];  const u16* cbl  = pp[7];
  const u16* clng = pp[8];  const u16* clnb = pp[9];
  const u16* cbng = pp[10]; const u16* cbnb = pp[11];
  const u16* cbnrm= pp[12]; const u16* cbnrv= pp[13];
  const u16* cgWh = pp[14]; const u16* cgbh = pp[15];
  const u16* cgWk = pp[16]; const u16* cgWv = pp[17];
  const u16* cglng= pp[18]; const u16* cglnb= pp[19];
  const u16* cgWo = pp[20]; const u16* cgbo = pp[21];
  const u16* cflng= pp[22]; const u16* cflnb= pp[23];
  const u16* cWp  = pp[24]; const u16* cbp  = pp[25];

  u16* xb  = (u16*)xlocal;                             // dead after first k_gemm3
  int* eib = (int*)((char*)xlocal + (size_t)Nn*C*2);   // dead after k_scatter8
  u16* xg  = x_cur;
  float* kvpart = xlocal;                              // 512*16512*4 = 33.8MB <= Nn*C*4

  const int NB_KV = 512;
  const int npb = (Nn + NB_KV - 1) / NB_KV;
  const int gblk = (Nn + 127) / 128;
  const int nodeblk = (Nn + 3) / 4;
  const int nscan = (Nn + 255) / 256;     // 391 for N=100k (must be <= 1024)
  const int NSL = 512;

  k_probe<<<1, 256, 0, stream>>>((const u32*)d_in[0], (const u32*)d_in[1], flags);
  hipMemsetAsync(cnt, 0, (size_t)Nn*4, stream);
  k_cvt_ei_count<<<(2*E + 255)/256, 256, 0, stream>>>((const int*)d_in[1], eib, E, flags, cnt);
  k_cvt_x<<<(Nn*C/8 + 255)/256, 256, 0, stream>>>(d_in[0], xb, Nn*C, flags);
  {
    CvtArgs a;
    int maxn = 0;
    for(int k=2;k<26;k++){
      a.src[k-2] = d_in[k];
      a.dst[k-2] = (u16*)pp[k];
      a.n[k-2]   = in_sizes[k];
      if(in_sizes[k] > maxn) maxn = in_sizes[k];
    }
    dim3 g((maxn + 255)/256, 24);
    k_cvt_params<<<g, 256, 0, stream>>>(a, flags);
  }

  k_scan1<<<nscan, 256, 0, stream>>>(cnt, Nn, bsum);
  k_scan2<<<1, 1024, 0, stream>>>(bsum, nscan, bpre);
  k_scan3<<<nscan, 256, 0, stream>>>(cnt, Nn, bpre, rowst, cursor, dinv);
  k_scatter8<<<NSL*8, 256, 0, stream>>>(eib, E, Nn, NSL, cursor, dinv, colw);

  const u16* xa = xb;
  for(int i=0; i<7; i++){
    k_gemm3<<<dim3(gblk,3), 256, 0, stream>>>(xa, Nn,
        cWh + (size_t)i*C*C, cbh + (size_t)i*C, 1, hb,
        cWg + (size_t)i*C*C, (const u16*)nullptr, 0, xwb,
        cWl + (size_t)i*C*C, cbl + (size_t)i*C, 0, xlb);
    k_layer_epi<<<nodeblk, 256, 0, stream>>>(xwb, hb, xlb, colw, rowst, dinv,
        cbg + (size_t)i*C, cbng + (size_t)i*C, cbnb + (size_t)i*C,
        cbnrm + (size_t)i*C, cbnrv + (size_t)i*C,
        clng + (size_t)i*C, clnb + (size_t)i*C,
        cflng, cflnb,
        xlocal, x_cur, Nn, (i==0) ? 1 : 0, (i==6) ? 1 : 0);
    xa = x_cur;
  }

  for(int j=0; j<2; j++){
    k_gemm3<<<dim3(gblk,3), 256, 0, stream>>>(xg, Nn,
        cgWh + (size_t)j*C*C, cgbh + (size_t)j*C, 0, hb,
        cgWk + (size_t)j*C*C, (const u16*)nullptr, 2, xwb,
        cgWv + (size_t)j*C*C, (const u16*)nullptr, 0, xlb);
    k_kv   <<<NB_KV, 256, 0, stream>>>(xwb, xlb, Nn, npb, kvpart);
    k_kvred<<<(144*128 + 255)/256, 256, 0, stream>>>(kvpart, NB_KV, Bext);
    k_attn <<<gblk, 256, 0, stream>>>(xwb, Bext, hb, cglng + (size_t)j*C, cglnb + (size_t)j*C, xlb, Nn);
    k_gemm3<<<dim3(gblk,1), 256, 0, stream>>>(xlb, Nn,
        cgWo + (size_t)j*C*C, cgbo + (size_t)j*C, 1, xg,
        (const u16*)nullptr, (const u16*)nullptr, 0, (u16*)nullptr,
        (const u16*)nullptr, (const u16*)nullptr, 0, (u16*)nullptr);
  }

  k_gout<<<gblk, 256, 0, stream>>>(xg, cWp, cbp, d_out, Nn, flags);
}

// Round 12
// 1697.201 us; speedup vs baseline: 1.0132x; 1.0132x over previous
//
#include <hip/hip_runtime.h>

typedef unsigned short u16;
typedef unsigned int u32;
typedef __attribute__((ext_vector_type(8))) short short8;
typedef __attribute__((ext_vector_type(8))) unsigned short ushort8v;
typedef __attribute__((ext_vector_type(4))) float f32x4;

#define CDIM 128

__device__ __forceinline__ float b2f(u16 u){ return __uint_as_float(((unsigned)u)<<16); }
__device__ __forceinline__ u16 f2b(float f){
  unsigned x = __float_as_uint(f);
  unsigned r = (x + 0x7fffu + ((x>>16)&1u)) >> 16;
  return (u16)r;
}
__device__ __forceinline__ float wsum64(float v){
  #pragma unroll
  for(int d=1; d<64; d<<=1) v += __shfl_xor(v, d, 64);
  return v;
}
__device__ __forceinline__ float wsum16(float v){
  v += __shfl_xor(v, 1, 64);
  v += __shfl_xor(v, 2, 64);
  v += __shfl_xor(v, 4, 64);
  v += __shfl_xor(v, 8, 64);
  return v;
}

// ---------------- dtype probe ----------------
__global__ void k_probe(const u32* __restrict__ x, const u32* __restrict__ ei, int* __restrict__ flags){
  __shared__ int s_bf, s_nz;
  if(threadIdx.x == 0){ s_bf = 0; s_nz = 0; }
  __syncthreads();
  int c_bf = 0, c_nz = 0;
  for(int i = threadIdx.x; i < 4096; i += 256){
    u32 w = x[i];
    u32 e = (w >> 7) & 0xFFu;
    if(e >= 100u && e <= 140u) c_bf++;
    if(ei[2*i + 1] != 0u) c_nz++;
  }
  atomicAdd(&s_bf, c_bf);
  atomicAdd(&s_nz, c_nz);
  __syncthreads();
  if(threadIdx.x == 0){
    flags[0] = (s_bf < 2048) ? 1 : 0;
    flags[1] = (s_nz < 8) ? 1 : 0;
  }
}

// ---------------- conversions ----------------
__global__ void k_cvt_x(const void* __restrict__ src, u16* __restrict__ dst, int n,
                        const int* __restrict__ flags){
  int i = (blockIdx.x*256 + threadIdx.x)*8;
  if(i + 7 >= n) return;
  if(flags[0]){
    const float* s = (const float*)src + i;
    float4 a = *(const float4*)s;
    float4 b = *(const float4*)(s + 4);
    ushort8v o;
    o[0]=f2b(a.x); o[1]=f2b(a.y); o[2]=f2b(a.z); o[3]=f2b(a.w);
    o[4]=f2b(b.x); o[5]=f2b(b.y); o[6]=f2b(b.z); o[7]=f2b(b.w);
    *(ushort8v*)(dst + i) = o;
  } else {
    *(ushort8v*)(dst + i) = *(const ushort8v*)((const u16*)src + i);
  }
}

struct CvtArgs {
  const void* src[24];
  u16* dst[24];
  int n[24];
};

__global__ void k_cvt_params(CvtArgs a, const int* __restrict__ flags){
  int seg = blockIdx.y;
  int i = blockIdx.x*256 + threadIdx.x;
  int n = a.n[seg];
  if(i >= n) return;
  if(flags[0]) a.dst[seg][i] = f2b(((const float*)a.src[seg])[i]);
  else         a.dst[seg][i] = ((const u16*)a.src[seg])[i];
}

// convert edge index (int64->int32 if needed) + count destination degrees in the same pass
__global__ void k_cvt_ei_count(const int* __restrict__ src, int* __restrict__ dst, int E,
                               const int* __restrict__ flags, u32* __restrict__ cnt){
  int i = blockIdx.x*256 + threadIdx.x;
  if(i >= 2*E) return;
  int v = flags[1] ? src[2*i] : src[i];
  dst[i] = v;
  if(i >= E) atomicAdd(&cnt[v], 1u);
}

// ---------------- multi-block exclusive scan of cnt -> rowstart (+cursor, dinv) ----------------
__global__ __launch_bounds__(256) void k_scan1(const u32* __restrict__ cnt, int n, u32* __restrict__ bsum){
  const int lane = threadIdx.x & 63;
  const int wv = threadIdx.x >> 6;
  int i = blockIdx.x*256 + threadIdx.x;
  u32 v = (i < n) ? cnt[i] : 0u;
  #pragma unroll
  for(int d=1; d<64; d<<=1) v += (u32)__shfl_xor((int)v, d, 64);
  __shared__ u32 ws[4];
  if(lane == 0) ws[wv] = v;
  __syncthreads();
  if(threadIdx.x == 0) bsum[blockIdx.x] = ws[0] + ws[1] + ws[2] + ws[3];
}

__global__ __launch_bounds__(1024) void k_scan2(const u32* __restrict__ bsum, int nb, u32* __restrict__ bpre){
  __shared__ u32 s[1024];
  int t = threadIdx.x;
  u32 v = (t < nb) ? bsum[t] : 0u;
  s[t] = v;
  __syncthreads();
  for(int d=1; d<1024; d<<=1){
    u32 y = (t >= d) ? s[t-d] : 0u;
    __syncthreads();
    s[t] += y;
    __syncthreads();
  }
  if(t < nb) bpre[t] = s[t] - v;   // exclusive
}

__global__ __launch_bounds__(256) void k_scan3(const u32* __restrict__ cnt, int n,
                                               const u32* __restrict__ bpre,
                                               u32* __restrict__ rowstart, u32* __restrict__ cursor,
                                               float* __restrict__ dinv){
  const int lane = threadIdx.x & 63;
  const int wv = threadIdx.x >> 6;
  int i = blockIdx.x*256 + threadIdx.x;
  u32 v = (i < n) ? cnt[i] : 0u;
  u32 x = v;
  #pragma unroll
  for(int d=1; d<64; d<<=1){
    u32 y = (u32)__shfl_up((int)x, d, 64);
    if(lane >= d) x += y;
  }
  __shared__ u32 ws[4];
  if(lane == 63) ws[wv] = x;
  __syncthreads();
  u32 woff = 0;
  #pragma unroll
  for(int w=0; w<4; w++) if(w < wv) woff += ws[w];
  u32 incl = x + woff;
  u32 rs = bpre[blockIdx.x] + incl - v;
  if(i < n){
    rowstart[i] = rs;
    cursor[i] = rs;
    dinv[i] = rsqrtf((float)(v + 1u));
    if(i == n-1) rowstart[n] = rs + v;
  }
}

// ---------------- dst-range-partitioned scatter ----------------
__global__ __launch_bounds__(256) void k_scatter8(
  const int* __restrict__ ei, int E, int Nn, int nsl,
  u32* __restrict__ cursor, const float* __restrict__ dinv, int2* __restrict__ colw)
{
  const int r = blockIdx.x & 7;
  const int slice = blockIdx.x >> 3;
  const int q = (Nn + 7) >> 3;
  const int lo = r*q;
  const int hi = (lo + q < Nn) ? lo + q : Nn;
  const int chunk = (E + nsl - 1) / nsl;
  int e0 = slice*chunk;
  int e1 = e0 + chunk; if(e1 > E) e1 = E;
  for(int e = e0 + threadIdx.x; e < e1; e += 256){
    int d = ei[E + e];
    if(d >= lo && d < hi){
      int s = ei[e];
      u32 p = atomicAdd(&cursor[d], 1u);
      colw[p] = make_int2(s, __float_as_int(dinv[s]));
    }
  }
}

// ---------------- fused GEMM, transposed-operand epilogue, weight picked by blockIdx.y (r10 version) ----------------
__global__ __launch_bounds__(256) void k_gemm3(
  const u16* __restrict__ A, int M,
  const u16* __restrict__ W0, const u16* __restrict__ bs0, int op0, u16* __restrict__ O0,
  const u16* __restrict__ W1, const u16* __restrict__ bs1, int op1, u16* __restrict__ O1,
  const u16* __restrict__ W2, const u16* __restrict__ bs2, int op2, u16* __restrict__ O2)
{
  const int lane = threadIdx.x & 63;
  const int wv = threadIdx.x >> 6;
  const int l16 = lane & 15, quad = lane >> 4;
  const long nbase = (long)blockIdx.x*128 + wv*32;

  const u16* Ws[3] = {W0, W1, W2};
  const u16* Bs[3] = {bs0, bs1, bs2};
  u16* Os[3] = {O0, O1, O2};
  const int ops[3] = {op0, op1, op2};
  const int w = blockIdx.y;
  const u16* Wm = Ws[w];
  const int op = ops[w];
  u16* Op = Os[w];
  const u16* bp = Bs[w];

  short8 xf[2][4];             // B-operand: node nbase+nt*16+l16, k = quad*8 + kt*32
  #pragma unroll
  for(int nt=0; nt<2; nt++){
    long r = nbase + nt*16 + l16; if(r >= M) r = M-1;
    const u16* ap = A + r*CDIM + quad*8;
    #pragma unroll
    for(int kt=0; kt<4; kt++)
      xf[nt][kt] = *(const short8*)(ap + kt*32);
  }

  #pragma unroll
  for(int ct=0; ct<8; ct++){
    f32x4 acc0 = {0.f,0.f,0.f,0.f}, acc1 = {0.f,0.f,0.f,0.f};
    const u16* wp = Wm + (ct*16 + l16)*CDIM + quad*8;   // A-operand: ch ct*16+l16, k quad*8+j
    #pragma unroll
    for(int kt=0; kt<4; kt++){
      short8 wf = *(const short8*)(wp + kt*32);
      acc0 = __builtin_amdgcn_mfma_f32_16x16x32_bf16(wf, xf[0][kt], acc0, 0, 0, 0);
      acc1 = __builtin_amdgcn_mfma_f32_16x16x32_bf16(wf, xf[1][kt], acc1, 0, 0, 0);
    }
    float bv[4] = {0.f,0.f,0.f,0.f};
    if(bp){
      ushort4 bq = *(const ushort4*)(bp + ct*16 + quad*4);
      bv[0]=b2f(bq.x); bv[1]=b2f(bq.y); bv[2]=b2f(bq.z); bv[3]=b2f(bq.w);
    }
    #pragma unroll
    for(int nt=0; nt<2; nt++){
      long node = nbase + nt*16 + l16;
      if(node < M){
        f32x4 a = nt ? acc1 : acc0;
        u16 o[4];
        #pragma unroll
        for(int g=0; g<4; g++){
          float v = a[g] + bv[g];
          if(op == 1) v = fmaxf(v, 0.f);
          else if(op == 2) v = 1.f/(1.f + __expf(-v));
          o[g] = f2b(v);
        }
        u32 p0 = (u32)o[0] | ((u32)o[1] << 16);
        u32 p1 = (u32)o[2] | ((u32)o[3] << 16);
        *(uint2*)(Op + (size_t)node*CDIM + ct*16 + quad*4) = make_uint2(p0, p1);
      }
    }
  }
}

// ---------------- per-layer: quad-per-edge gather + LDS redistribute + 2ch/lane epilogue ----------------
__global__ __launch_bounds__(256) void k_layer_epi(
  const u16* __restrict__ xw, const u16* __restrict__ h, const u16* __restrict__ xl,
  const int2* __restrict__ colw, const u32* __restrict__ rowstart, const float* __restrict__ dinv,
  const u16* __restrict__ bg, const u16* __restrict__ bng, const u16* __restrict__ bnb,
  const u16* __restrict__ bnrm, const u16* __restrict__ bnrv,
  const u16* __restrict__ lng, const u16* __restrict__ lnb,
  const u16* __restrict__ flng, const u16* __restrict__ flnb,
  float* __restrict__ xlocal, u16* __restrict__ xout, int n, int first, int final)
{
  __shared__ float redis[4][128];
  const int lane = threadIdx.x & 63;
  const int quad = lane >> 4;
  const int l16 = lane & 15;
  const int wv = threadIdx.x >> 6;
  int node = blockIdx.x*4 + wv;
  const int valid = (node < n);
  if(!valid) node = n - 1;
  const int cg = l16*8;
  u32 j0 = rowstart[node], j1 = rowstart[node+1];
  float a[8];
  #pragma unroll
  for(int g=0; g<8; g++) a[g] = 0.f;

  for(u32 base = j0; base < j1; base += 64){
    int avail = (int)(j1 - base);
    int cnt = avail < 64 ? avail : 64;
    int2 pw = make_int2(0, 0);              // pad: src 0 (valid row), w = +0.0f
    if(lane < cnt) pw = colw[base + lane];
    int cntp = (cnt + 15) & ~15;
    for(int t = 0; t < cntp; t += 16){
      int s[4]; float w[4]; ushort8v v[4];
      #pragma unroll
      for(int u=0; u<4; u++){
        s[u] = __shfl(pw.x, t + u*4 + quad, 64);
        w[u] = __int_as_float(__shfl(pw.y, t + u*4 + quad, 64));
      }
      #pragma unroll
      for(int u=0; u<4; u++) v[u] = *(const ushort8v*)(xw + (size_t)s[u]*CDIM + cg);
      #pragma unroll
      for(int u=0; u<4; u++){
        #pragma unroll
        for(int g=0; g<8; g++) a[g] = fmaf(w[u], b2f(v[u][g]), a[g]);
      }
    }
  }
  #pragma unroll
  for(int g=0; g<8; g++){
    a[g] += __shfl_xor(a[g], 16, 64);
    a[g] += __shfl_xor(a[g], 32, 64);
  }
  if(quad == 0){
    *(float4*)&redis[wv][cg]     = make_float4(a[0],a[1],a[2],a[3]);
    *(float4*)&redis[wv][cg + 4] = make_float4(a[4],a[5],a[6],a[7]);
  }
  __syncthreads();
  const int c0 = lane*2;
  float2 av = *(float2*)&redis[wv][c0];
  float a0 = av.x, a1 = av.y;

  float dn = dinv[node], sw = dn*dn;
  size_t base = (size_t)node*CDIM + c0;
  ushort2 xwv = *(const ushort2*)(xw + base);
  ushort2 xlv = *(const ushort2*)(xl + base);
  ushort2 hv  = *(const ushort2*)(h  + base);
  float x10 = a0*dn + b2f(xwv.x)*sw + b2f(bg[c0])   + b2f(xlv.x);
  float x11 = a1*dn + b2f(xwv.y)*sw + b2f(bg[c0+1]) + b2f(xlv.y);
  float s0 = rsqrtf(b2f(bnrv[c0])   + 1e-5f) * b2f(bng[c0]);
  float s1 = rsqrtf(b2f(bnrv[c0+1]) + 1e-5f) * b2f(bng[c0+1]);
  float x20 = (x10 - b2f(bnrm[c0]))*s0   + b2f(bnb[c0]);
  float x21 = (x11 - b2f(bnrm[c0+1]))*s1 + b2f(bnb[c0+1]);
  float x30 = fmaxf(x20, 0.f);
  float x31 = fmaxf(x21, 0.f);
  float t0 = b2f(hv.x)*x30, t1 = b2f(hv.y)*x31;
  float mu = wsum64(t0 + t1) * (1.f/128.f);
  float d0 = t0 - mu, d1 = t1 - mu;
  float var = wsum64(d0*d0 + d1*d1) * (1.f/128.f);
  float inv = rsqrtf(var + 1e-5f);
  float y0 = d0*inv*b2f(lng[c0])   + b2f(lnb[c0]);
  float y1 = d1*inv*b2f(lng[c0+1]) + b2f(lnb[c0+1]);
  float xn0 = 0.1f*y0 + 0.9f*x30;
  float xn1 = 0.1f*y1 + 0.9f*x31;
  float2 xl2;
  if(first){
    xl2.x = xn0; xl2.y = xn1;
  } else {
    xl2 = *(float2*)(xlocal + base);
    xl2.x += xn0; xl2.y += xn1;
  }
  if(!final){
    if(valid){
      *(float2*)(xlocal + base) = xl2;
      ushort2 o; o.x = f2b(xn0); o.y = f2b(xn1);
      *(ushort2*)(xout + base) = o;
    }
  } else {
    float mu2 = wsum64(xl2.x + xl2.y) * (1.f/128.f);
    float e0 = xl2.x - mu2, e1 = xl2.y - mu2;
    float var2 = wsum64(e0*e0 + e1*e1) * (1.f/128.f);
    float inv2 = rsqrtf(var2 + 1e-5f);
    if(valid){
      ushort2 o;
      o.x = f2b(e0*inv2*b2f(flng[c0])   + b2f(flnb[c0]));
      o.y = f2b(e1*inv2*b2f(flng[c0+1]) + b2f(flnb[c0+1]));
      *(ushort2*)(xout + base) = o;
    }
  }
}

// ---------------- kv = k^T v partials (+ k column sums) ----------------
__global__ __launch_bounds__(256) void k_kv(
  const u16* __restrict__ kk, const u16* __restrict__ vv, int n, int npb,
  float* __restrict__ part)
{
  __shared__ float sk[8][128];
  __shared__ float sv[8][128];
  const int tid = threadIdx.x;
  const int tr = tid >> 4, tc = tid & 15;
  float acc[8][8];
  #pragma unroll
  for(int i=0;i<8;i++){
    #pragma unroll
    for(int j=0;j<8;j++) acc[i][j] = 0.f;
  }
  float ks[8];
  #pragma unroll
  for(int i=0;i<8;i++) ks[i] = 0.f;
  int start = blockIdx.x * npb;
  int end = start + npb; if(end > n) end = n;
  const int lr = tid >> 5;
  const int lc = (tid & 31) * 4;
  for(int g0 = start; g0 < end; g0 += 8){
    int cnt = end - g0; if(cnt > 8) cnt = 8;
    __syncthreads();
    if(lr < cnt){
      ushort4 kq = *(const ushort4*)(kk + (size_t)(g0+lr)*CDIM + lc);
      ushort4 vq = *(const ushort4*)(vv + (size_t)(g0+lr)*CDIM + lc);
      sk[lr][lc] = b2f(kq.x); sk[lr][lc+1] = b2f(kq.y); sk[lr][lc+2] = b2f(kq.z); sk[lr][lc+3] = b2f(kq.w);
      sv[lr][lc] = b2f(vq.x); sv[lr][lc+1] = b2f(vq.y); sv[lr][lc+2] = b2f(vq.z); sv[lr][lc+3] = b2f(vq.w);
    }
    __syncthreads();
    for(int r=0; r<cnt; r++){
      float4 ka = *(const float4*)&sk[r][tr*8];
      float4 kb = *(const float4*)&sk[r][tr*8+4];
      float4 va = *(const float4*)&sv[r][tc*8];
      float4 vb = *(const float4*)&sv[r][tc*8+4];
      float kr[8] = {ka.x,ka.y,ka.z,ka.w,kb.x,kb.y,kb.z,kb.w};
      float vr[8] = {va.x,va.y,va.z,va.w,vb.x,vb.y,vb.z,vb.w};
      #pragma unroll
      for(int i=0;i<8;i++){
        #pragma unroll
        for(int j=0;j<8;j++) acc[i][j] = fmaf(kr[i], vr[j], acc[i][j]);
      }
      if(tc == 0){
        #pragma unroll
        for(int i=0;i<8;i++) ks[i] += kr[i];
      }
    }
  }
  float* p = part + (size_t)blockIdx.x * 16512;
  #pragma unroll
  for(int i=0;i<8;i++){
    #pragma unroll
    for(int j=0;j<8;j++)
      p[(size_t)(tc*8+j)*CDIM + tr*8 + i] = acc[i][j];
  }
  if(tc == 0){
    #pragma unroll
    for(int i=0;i<8;i++) p[16384 + tr*8 + i] = ks[i];
  }
}

// reduce partials -> Bext bf16 [144][128]
__global__ void k_kvred(const float* __restrict__ part, int nb, u16* __restrict__ Bext){
  int i = blockIdx.x*256 + threadIdx.x;
  if(i >= 144*128) return;
  float s = 0.f;
  if(i < 16512){
    #pragma unroll 8
    for(int b=0;b<nb;b++) s += part[(size_t)b*16512 + i];
  }
  Bext[i] = f2b(s);
}

// ---------------- fused attention tail: num GEMM + den + LN + x(h+0.9) + gWo GEMM + relu
//                  (+ final Wp projection when last) ----------------
// All stages row-local within a wave's 32-node tile; LDS is wave-private (no syncthreads).
__global__ __launch_bounds__(256) void k_attn(
  const u16* __restrict__ q, const u16* __restrict__ Bext, const u16* __restrict__ hg,
  const u16* __restrict__ g, const u16* __restrict__ b,
  const u16* __restrict__ Wo, const u16* __restrict__ bo,
  const u16* __restrict__ Wp, const u16* __restrict__ bp,
  u16* __restrict__ xgout, void* __restrict__ outv,
  int M, int last, const int* __restrict__ flags)
{
  __shared__ u16 stg[4][32*136];
  const int lane = threadIdx.x & 63;
  const int wv = threadIdx.x >> 6;
  const int l16 = lane & 15, quad = lane >> 4;
  const long rbase = (long)blockIdx.x*128 + wv*32;
  u16* st = stg[wv];

  // ---- stage 1: num/den GEMM + LN -> y staged in LDS ----
  {
    short8 af[2][4];
    #pragma unroll
    for(int rt=0; rt<2; rt++){
      long r = rbase + rt*16 + l16; if(r >= M) r = M-1;
      const u16* ap = q + r*CDIM + quad*8;
      #pragma unroll
      for(int kt=0; kt<4; kt++)
        af[rt][kt] = *(const short8*)(ap + kt*32);
    }
    f32x4 acc[2][9];
    f32x4 zero = {0.f,0.f,0.f,0.f};
    #pragma unroll
    for(int rt=0; rt<2; rt++){
      #pragma unroll
      for(int ct=0; ct<9; ct++) acc[rt][ct] = zero;
    }
    #pragma unroll
    for(int ct=0; ct<9; ct++){
      const u16* wp = Bext + (ct*16 + l16)*CDIM + quad*8;
      #pragma unroll
      for(int kt=0; kt<4; kt++){
        short8 bf = *(const short8*)(wp + kt*32);
        acc[0][ct] = __builtin_amdgcn_mfma_f32_16x16x32_bf16(af[0][kt], bf, acc[0][ct], 0, 0, 0);
        acc[1][ct] = __builtin_amdgcn_mfma_f32_16x16x32_bf16(af[1][kt], bf, acc[1][ct], 0, 0, 0);
      }
    }
    #pragma unroll
    for(int rt=0; rt<2; rt++){
      float rden[4];
      #pragma unroll
      for(int gi=0; gi<4; gi++){
        float dv = __shfl(acc[rt][8][gi], lane & 48, 64);
        rden[gi] = 1.f/(dv + 1e-6f);
      }
      #pragma unroll
      for(int gi=0; gi<4; gi++){
        float sum = 0.f;
        #pragma unroll
        for(int ct=0; ct<8; ct++) sum += acc[rt][ct][gi]*rden[gi];
        float mu = wsum16(sum) * (1.f/128.f);
        float vs = 0.f;
        #pragma unroll
        for(int ct=0; ct<8; ct++){ float d = acc[rt][ct][gi]*rden[gi] - mu; vs = fmaf(d, d, vs); }
        float inv = rsqrtf(wsum16(vs)*(1.f/128.f) + 1e-5f);
        const int rowl = rt*16 + quad*4 + gi;
        #pragma unroll
        for(int ct=0; ct<8; ct++){
          int col = ct*16 + l16;
          float y = (acc[rt][ct][gi]*rden[gi] - mu)*inv*b2f(g[col]) + b2f(b[col]);
          st[rowl*136 + col] = f2b(y);
        }
      }
    }
  }
  // ---- stage 2: y *= (h + 0.9), coalesced hg reads, in-place in LDS ----
  #pragma unroll
  for(int p2=0; p2<8; p2++){
    int row = (p2>>2)*16 + (lane>>2);
    int seg = (lane&3) + (p2&3)*4;
    long node = rbase + row;
    if(node >= M) node = M-1;
    ushort8v yv = *(const ushort8v*)&st[row*136 + seg*8];
    ushort8v hv = *(const ushort8v*)(hg + (size_t)node*CDIM + seg*8);
    ushort8v o;
    #pragma unroll
    for(int i2=0; i2<8; i2++)
      o[i2] = f2b(b2f(yv[i2]) * (b2f(hv[i2]) + 0.9f));
    *(ushort8v*)&st[row*136 + seg*8] = o;
  }
  // ---- stage 3: p-fragments from LDS (B-operand layout) ----
  short8 pf[2][4];
  #pragma unroll
  for(int nt=0; nt<2; nt++){
    #pragma unroll
    for(int kt=0; kt<4; kt++)
      pf[nt][kt] = *(const short8*)&st[(nt*16 + l16)*136 + quad*8 + kt*32];
  }
  // ---- stage 4: out2 = relu(p @ Wo^T + bo), restaged into LDS ----
  #pragma unroll
  for(int ct=0; ct<8; ct++){
    f32x4 a0 = {0.f,0.f,0.f,0.f}, a1 = {0.f,0.f,0.f,0.f};
    const u16* wp = Wo + (ct*16 + l16)*CDIM + quad*8;
    #pragma unroll
    for(int kt=0; kt<4; kt++){
      short8 wf = *(const short8*)(wp + kt*32);
      a0 = __builtin_amdgcn_mfma_f32_16x16x32_bf16(wf, pf[0][kt], a0, 0, 0, 0);
      a1 = __builtin_amdgcn_mfma_f32_16x16x32_bf16(wf, pf[1][kt], a1, 0, 0, 0);
    }
    ushort4 bq = *(const ushort4*)(bo + ct*16 + quad*4);
    float bv[4] = {b2f(bq.x), b2f(bq.y), b2f(bq.z), b2f(bq.w)};
    #pragma unroll
    for(int nt=0; nt<2; nt++){
      f32x4 a = nt ? a1 : a0;
      u16 o[4];
      #pragma unroll
      for(int g2=0; g2<4; g2++)
        o[g2] = f2b(fmaxf(a[g2] + bv[g2], 0.f));
      u32 p0 = (u32)o[0] | ((u32)o[1] << 16);
      u32 p1 = (u32)o[2] | ((u32)o[3] << 16);
      *(uint2*)&st[(nt*16 + l16)*136 + ct*16 + quad*4] = make_uint2(p0, p1);
    }
  }
  if(!last){
    // ---- stage 5a: coalesced copy-out to xg ----
    #pragma unroll
    for(int p2=0; p2<8; p2++){
      int row = (p2>>2)*16 + (lane>>2);
      int seg = (lane&3) + (p2&3)*4;
      long node = rbase + row;
      ushort8v v = *(const ushort8v*)&st[row*136 + seg*8];
      if(node < M)
        *(ushort8v*)(xgout + (size_t)node*CDIM + seg*8) = v;
    }
  } else {
    // ---- stage 5b: final projection out = p2 @ Wp^T + bp (40 cols) ----
    const int f32m = flags[0];
    short8 pf2[2][4];
    #pragma unroll
    for(int nt=0; nt<2; nt++){
      #pragma unroll
      for(int kt=0; kt<4; kt++)
        pf2[nt][kt] = *(const short8*)&st[(nt*16 + l16)*136 + quad*8 + kt*32];
    }
    #pragma unroll
    for(int ct=0; ct<3; ct++){
      f32x4 a0 = {0.f,0.f,0.f,0.f}, a1 = {0.f,0.f,0.f,0.f};
      int wrow = ct*16 + l16; if(wrow > 39) wrow = 39;
      const u16* wp = Wp + wrow*CDIM + quad*8;
      #pragma unroll
      for(int kt=0; kt<4; kt++){
        short8 wf = *(const short8*)(wp + kt*32);
        a0 = __builtin_amdgcn_mfma_f32_16x16x32_bf16(wf, pf2[0][kt], a0, 0, 0, 0);
        a1 = __builtin_amdgcn_mfma_f32_16x16x32_bf16(wf, pf2[1][kt], a1, 0, 0, 0);
      }
      const int ch0 = ct*16 + quad*4;
      if(ch0 < 40){
        ushort4 bq = *(const ushort4*)(bp + ch0);
        float bv[4] = {b2f(bq.x), b2f(bq.y), b2f(bq.z), b2f(bq.w)};
        #pragma unroll
        for(int nt=0; nt<2; nt++){
          long node = rbase + nt*16 + l16;
          if(node < M){
            f32x4 a = nt ? a1 : a0;
            if(f32m){
              float* op = (float*)outv + node*40 + ch0;
              #pragma unroll
              for(int g2=0; g2<4; g2++) op[g2] = a[g2] + bv[g2];
            } else {
              u16 o[4];
              #pragma unroll
              for(int g2=0; g2<4; g2++) o[g2] = f2b(a[g2] + bv[g2]);
              u32 p0 = (u32)o[0] | ((u32)o[1] << 16);
              u32 p1 = (u32)o[2] | ((u32)o[3] << 16);
              *(uint2*)((u16*)outv + node*40 + ch0) = make_uint2(p0, p1);
            }
          }
        }
      }
    }
  }
}

extern "C" void kernel_launch(void* const* d_in, const int* in_sizes, int n_in,
                              void* d_out, int out_size, void* d_ws, size_t ws_size,
                              hipStream_t stream)
{
  (void)n_in;
  const int C = CDIM;
  const int Nn = in_sizes[0] / C;
  const int E  = in_sizes[1] / 2;

  char* ws = (char*)d_ws;
  size_t off = 0;
  auto alloc = [&](size_t bytes) -> char* {
    char* p = ws + off;
    off = (off + bytes + 255) & ~(size_t)255;
    return p;
  };
  u16*   x_cur  = (u16*)  alloc((size_t)Nn*C*2);     // also xg after final epi
  float* xlocal = (float*)alloc((size_t)Nn*C*4);     // early: [xb bf16 | eib]; then accum; then kvpart
  u16*   hb     = (u16*)  alloc((size_t)Nn*C*2);
  u16*   xwb    = (u16*)  alloc((size_t)Nn*C*2);
  u16*   xlb    = (u16*)  alloc((size_t)Nn*C*2);
  float* dinv   = (float*)alloc((size_t)Nn*4);
  u32*   cnt    = (u32*)  alloc((size_t)Nn*4);
  u32*   rowst  = (u32*)  alloc((size_t)(Nn+1)*4);
  u32*   cursor = (u32*)  alloc((size_t)Nn*4);
  int2*  colw   = (int2*) alloc((size_t)E*8);
  u16*   Bext   = (u16*)  alloc((size_t)144*128*2);
  int*   flags  = (int*)  alloc(256);
  u32*   bsum   = (u32*)  alloc(1024*4);
  u32*   bpre   = (u32*)  alloc(1024*4);
  size_t ptot = 0;
  for(int k=2;k<26;k++) ptot += (size_t)in_sizes[k];
  u16* pbuf = (u16*)alloc(ptot*2);

  if(off > ws_size){
    hipMemsetAsync(d_out, 0, (size_t)out_size*2, stream);
    return;
  }

  const u16* pp[26];
  {
    size_t po = 0;
    for(int k=2;k<26;k++){ pp[k] = pbuf + po; po += (size_t)in_sizes[k]; }
  }
  const u16* cWh  = pp[2];  const u16* cbh  = pp[3];
  const u16* cWg  = pp[4];  const u16* cbg  = pp[5];
  const u16* cWl  = pp[6];  const u16* cbl  = pp[7];
  const u16* clng = pp[8];  const u16* clnb = pp[9];
  const u16* cbng = pp[10]; const u16* cbnb = pp[11];
  const u16* cbnrm= pp[12]; const u16* cbnrv= pp[13];
  const u16* cgWh = pp[14]; const u16* cgbh = pp[15];
  const u16* cgWk = pp[16]; const u16* cgWv = pp[17];
  const u16* cglng= pp[18]; const u16* cglnb= pp[19];
  const u16* cgWo = pp[20]; const u16* cgbo = pp[21];
  const u16* cflng= pp[22]; const u16* cflnb= pp[23];
  const u16* cWp  = pp[24]; const u16* cbp  = pp[25];

  u16* xb  = (u16*)xlocal;                             // dead after first k_gemm3
  int* eib = (int*)((char*)xlocal + (size_t)Nn*C*2);   // dead after k_scatter8
  u16* xg  = x_cur;
  float* kvpart = xlocal;                              // 512*16512*4 = 33.8MB <= Nn*C*4

  const int NB_KV = 512;
  const int npb = (Nn + NB_KV - 1) / NB_KV;
  const int gblk = (Nn + 127) / 128;
  const int nodeblk = (Nn + 3) / 4;
  const int nscan = (Nn + 255) / 256;     // 391 for N=100k (must be <= 1024)
  const int NSL = 512;

  k_probe<<<1, 256, 0, stream>>>((const u32*)d_in[0], (const u32*)d_in[1], flags);
  hipMemsetAsync(cnt, 0, (size_t)Nn*4, stream);
  k_cvt_ei_count<<<(2*E + 255)/256, 256, 0, stream>>>((const int*)d_in[1], eib, E, flags, cnt);
  k_cvt_x<<<(Nn*C/8 + 255)/256, 256, 0, stream>>>(d_in[0], xb, Nn*C, flags);
  {
    CvtArgs a;
    int maxn = 0;
    for(int k=2;k<26;k++){
      a.src[k-2] = d_in[k];
      a.dst[k-2] = (u16*)pp[k];
      a.n[k-2]   = in_sizes[k];
      if(in_sizes[k] > maxn) maxn = in_sizes[k];
    }
    dim3 g((maxn + 255)/256, 24);
    k_cvt_params<<<g, 256, 0, stream>>>(a, flags);
  }

  k_scan1<<<nscan, 256, 0, stream>>>(cnt, Nn, bsum);
  k_scan2<<<1, 1024, 0, stream>>>(bsum, nscan, bpre);
  k_scan3<<<nscan, 256, 0, stream>>>(cnt, Nn, bpre, rowst, cursor, dinv);
  k_scatter8<<<NSL*8, 256, 0, stream>>>(eib, E, Nn, NSL, cursor, dinv, colw);

  const u16* xa = xb;
  for(int i=0; i<7; i++){
    k_gemm3<<<dim3(gblk,3), 256, 0, stream>>>(xa, Nn,
        cWh + (size_t)i*C*C, cbh + (size_t)i*C, 1, hb,
        cWg + (size_t)i*C*C, (const u16*)nullptr, 0, xwb,
        cWl + (size_t)i*C*C, cbl + (size_t)i*C, 0, xlb);
    k_layer_epi<<<nodeblk, 256, 0, stream>>>(xwb, hb, xlb, colw, rowst, dinv,
        cbg + (size_t)i*C, cbng + (size_t)i*C, cbnb + (size_t)i*C,
        cbnrm + (size_t)i*C, cbnrv + (size_t)i*C,
        clng + (size_t)i*C, clnb + (size_t)i*C,
        cflng, cflnb,
        xlocal, x_cur, Nn, (i==0) ? 1 : 0, (i==6) ? 1 : 0);
    xa = x_cur;
  }

  for(int j=0; j<2; j++){
    k_gemm3<<<dim3(gblk,3), 256, 0, stream>>>(xg, Nn,
        cgWh + (size_t)j*C*C, cgbh + (size_t)j*C, 0, hb,
        cgWk + (size_t)j*C*C, (const u16*)nullptr, 2, xwb,
        cgWv + (size_t)j*C*C, (const u16*)nullptr, 0, xlb);
    k_kv   <<<NB_KV, 256, 0, stream>>>(xwb, xlb, Nn, npb, kvpart);
    k_kvred<<<(144*128 + 255)/256, 256, 0, stream>>>(kvpart, NB_KV, Bext);
    k_attn <<<gblk, 256, 0, stream>>>(xwb, Bext, hb,
        cglng + (size_t)j*C, cglnb + (size_t)j*C,
        cgWo + (size_t)j*C*C, cgbo + (size_t)j*C,
        cWp, cbp, xg, d_out, Nn, (j==1) ? 1 : 0, flags);
  }
}

// Round 13
// 1653.346 us; speedup vs baseline: 1.0401x; 1.0265x over previous
//
#include <hip/hip_runtime.h>

typedef unsigned short u16;
typedef unsigned int u32;
typedef __attribute__((ext_vector_type(8))) short short8;
typedef __attribute__((ext_vector_type(8))) unsigned short ushort8v;
typedef __attribute__((ext_vector_type(4))) float f32x4;

#define CDIM 128

__device__ __forceinline__ float b2f(u16 u){ return __uint_as_float(((unsigned)u)<<16); }
__device__ __forceinline__ u16 f2b(float f){
  unsigned x = __float_as_uint(f);
  unsigned r = (x + 0x7fffu + ((x>>16)&1u)) >> 16;
  return (u16)r;
}
__device__ __forceinline__ float wsum64(float v){
  #pragma unroll
  for(int d=1; d<64; d<<=1) v += __shfl_xor(v, d, 64);
  return v;
}
__device__ __forceinline__ float wsum16(float v){
  v += __shfl_xor(v, 1, 64);
  v += __shfl_xor(v, 2, 64);
  v += __shfl_xor(v, 4, 64);
  v += __shfl_xor(v, 8, 64);
  return v;
}

// ---------------- dtype probe ----------------
__global__ void k_probe(const u32* __restrict__ x, const u32* __restrict__ ei, int* __restrict__ flags){
  __shared__ int s_bf, s_nz;
  if(threadIdx.x == 0){ s_bf = 0; s_nz = 0; }
  __syncthreads();
  int c_bf = 0, c_nz = 0;
  for(int i = threadIdx.x; i < 4096; i += 256){
    u32 w = x[i];
    u32 e = (w >> 7) & 0xFFu;
    if(e >= 100u && e <= 140u) c_bf++;
    if(ei[2*i + 1] != 0u) c_nz++;
  }
  atomicAdd(&s_bf, c_bf);
  atomicAdd(&s_nz, c_nz);
  __syncthreads();
  if(threadIdx.x == 0){
    flags[0] = (s_bf < 2048) ? 1 : 0;
    flags[1] = (s_nz < 8) ? 1 : 0;
  }
}

// ---------------- conversions ----------------
__global__ void k_cvt_x(const void* __restrict__ src, u16* __restrict__ dst, int n,
                        const int* __restrict__ flags){
  int i = (blockIdx.x*256 + threadIdx.x)*8;
  if(i + 7 >= n) return;
  if(flags[0]){
    const float* s = (const float*)src + i;
    float4 a = *(const float4*)s;
    float4 b = *(const float4*)(s + 4);
    ushort8v o;
    o[0]=f2b(a.x); o[1]=f2b(a.y); o[2]=f2b(a.z); o[3]=f2b(a.w);
    o[4]=f2b(b.x); o[5]=f2b(b.y); o[6]=f2b(b.z); o[7]=f2b(b.w);
    *(ushort8v*)(dst + i) = o;
  } else {
    *(ushort8v*)(dst + i) = *(const ushort8v*)((const u16*)src + i);
  }
}

struct CvtArgs {
  const void* src[24];
  u16* dst[24];
  int n[24];
};

__global__ void k_cvt_params(CvtArgs a, const int* __restrict__ flags){
  int seg = blockIdx.y;
  int i = blockIdx.x*256 + threadIdx.x;
  int n = a.n[seg];
  if(i >= n) return;
  if(flags[0]) a.dst[seg][i] = f2b(((const float*)a.src[seg])[i]);
  else         a.dst[seg][i] = ((const u16*)a.src[seg])[i];
}

// convert edge index (int64->int32 if needed) + count destination degrees in the same pass
__global__ void k_cvt_ei_count(const int* __restrict__ src, int* __restrict__ dst, int E,
                               const int* __restrict__ flags, u32* __restrict__ cnt){
  int i = blockIdx.x*256 + threadIdx.x;
  if(i >= 2*E) return;
  int v = flags[1] ? src[2*i] : src[i];
  dst[i] = v;
  if(i >= E) atomicAdd(&cnt[v], 1u);
}

// ---------------- multi-block exclusive scan of cnt -> rowstart (+cursor, dinv) ----------------
__global__ __launch_bounds__(256) void k_scan1(const u32* __restrict__ cnt, int n, u32* __restrict__ bsum){
  const int lane = threadIdx.x & 63;
  const int wv = threadIdx.x >> 6;
  int i = blockIdx.x*256 + threadIdx.x;
  u32 v = (i < n) ? cnt[i] : 0u;
  #pragma unroll
  for(int d=1; d<64; d<<=1) v += (u32)__shfl_xor((int)v, d, 64);
  __shared__ u32 ws[4];
  if(lane == 0) ws[wv] = v;
  __syncthreads();
  if(threadIdx.x == 0) bsum[blockIdx.x] = ws[0] + ws[1] + ws[2] + ws[3];
}

__global__ __launch_bounds__(1024) void k_scan2(const u32* __restrict__ bsum, int nb, u32* __restrict__ bpre){
  __shared__ u32 s[1024];
  int t = threadIdx.x;
  u32 v = (t < nb) ? bsum[t] : 0u;
  s[t] = v;
  __syncthreads();
  for(int d=1; d<1024; d<<=1){
    u32 y = (t >= d) ? s[t-d] : 0u;
    __syncthreads();
    s[t] += y;
    __syncthreads();
  }
  if(t < nb) bpre[t] = s[t] - v;   // exclusive
}

__global__ __launch_bounds__(256) void k_scan3(const u32* __restrict__ cnt, int n,
                                               const u32* __restrict__ bpre,
                                               u32* __restrict__ rowstart, u32* __restrict__ cursor,
                                               float* __restrict__ dinv){
  const int lane = threadIdx.x & 63;
  const int wv = threadIdx.x >> 6;
  int i = blockIdx.x*256 + threadIdx.x;
  u32 v = (i < n) ? cnt[i] : 0u;
  u32 x = v;
  #pragma unroll
  for(int d=1; d<64; d<<=1){
    u32 y = (u32)__shfl_up((int)x, d, 64);
    if(lane >= d) x += y;
  }
  __shared__ u32 ws[4];
  if(lane == 63) ws[wv] = x;
  __syncthreads();
  u32 woff = 0;
  #pragma unroll
  for(int w=0; w<4; w++) if(w < wv) woff += ws[w];
  u32 incl = x + woff;
  u32 rs = bpre[blockIdx.x] + incl - v;
  if(i < n){
    rowstart[i] = rs;
    cursor[i] = rs;
    dinv[i] = rsqrtf((float)(v + 1u));
    if(i == n-1) rowstart[n] = rs + v;
  }
}

// ---------------- dst-range-partitioned scatter ----------------
__global__ __launch_bounds__(256) void k_scatter8(
  const int* __restrict__ ei, int E, int Nn, int nsl,
  u32* __restrict__ cursor, const float* __restrict__ dinv, int2* __restrict__ colw)
{
  const int r = blockIdx.x & 7;
  const int slice = blockIdx.x >> 3;
  const int q = (Nn + 7) >> 3;
  const int lo = r*q;
  const int hi = (lo + q < Nn) ? lo + q : Nn;
  const int chunk = (E + nsl - 1) / nsl;
  int e0 = slice*chunk;
  int e1 = e0 + chunk; if(e1 > E) e1 = E;
  for(int e = e0 + threadIdx.x; e < e1; e += 256){
    int d = ei[E + e];
    if(d >= lo && d < hi){
      int s = ei[e];
      u32 p = atomicAdd(&cursor[d], 1u);
      colw[p] = make_int2(s, __float_as_int(dinv[s]));
    }
  }
}

// ---------------- fused GEMM: 64 nodes/wave (nt=4), transposed-operand, weight by blockIdx.y ----------------
// Each weight-frag load feeds 4 independent MFMAs (vs 2): half the load instrs, 2x the
// acc-chain ILP — attacks r7's latency-bound profile (all pipes <11%).
__global__ __launch_bounds__(256) void k_gemm3(
  const u16* __restrict__ A, int M,
  const u16* __restrict__ W0, const u16* __restrict__ bs0, int op0, u16* __restrict__ O0,
  const u16* __restrict__ W1, const u16* __restrict__ bs1, int op1, u16* __restrict__ O1,
  const u16* __restrict__ W2, const u16* __restrict__ bs2, int op2, u16* __restrict__ O2)
{
  const int lane = threadIdx.x & 63;
  const int wv = threadIdx.x >> 6;
  const int l16 = lane & 15, quad = lane >> 4;
  const long nbase = (long)blockIdx.x*256 + wv*64;

  const u16* Ws[3] = {W0, W1, W2};
  const u16* Bs[3] = {bs0, bs1, bs2};
  u16* Os[3] = {O0, O1, O2};
  const int ops[3] = {op0, op1, op2};
  const int w = blockIdx.y;
  const u16* Wm = Ws[w];
  const int op = ops[w];
  u16* Op = Os[w];
  const u16* bp = Bs[w];

  short8 xf[4][4];             // B-operand: node nbase+nt*16+l16, k = quad*8 + kt*32
  #pragma unroll
  for(int nt=0; nt<4; nt++){
    long r = nbase + nt*16 + l16; if(r >= M) r = M-1;
    const u16* ap = A + r*CDIM + quad*8;
    #pragma unroll
    for(int kt=0; kt<4; kt++)
      xf[nt][kt] = *(const short8*)(ap + kt*32);
  }

  #pragma unroll
  for(int ct=0; ct<8; ct++){
    f32x4 acc[4];
    #pragma unroll
    for(int nt=0; nt<4; nt++) acc[nt] = (f32x4){0.f,0.f,0.f,0.f};
    const u16* wp = Wm + (ct*16 + l16)*CDIM + quad*8;   // A-operand: ch ct*16+l16, k quad*8+j
    #pragma unroll
    for(int kt=0; kt<4; kt++){
      short8 wf = *(const short8*)(wp + kt*32);
      #pragma unroll
      for(int nt=0; nt<4; nt++)
        acc[nt] = __builtin_amdgcn_mfma_f32_16x16x32_bf16(wf, xf[nt][kt], acc[nt], 0, 0, 0);
    }
    float bv[4] = {0.f,0.f,0.f,0.f};
    if(bp){
      ushort4 bq = *(const ushort4*)(bp + ct*16 + quad*4);
      bv[0]=b2f(bq.x); bv[1]=b2f(bq.y); bv[2]=b2f(bq.z); bv[3]=b2f(bq.w);
    }
    #pragma unroll
    for(int nt=0; nt<4; nt++){
      long node = nbase + nt*16 + l16;
      if(node < M){
        u16 o[4];
        #pragma unroll
        for(int g=0; g<4; g++){
          float v = acc[nt][g] + bv[g];
          if(op == 1) v = fmaxf(v, 0.f);
          else if(op == 2) v = 1.f/(1.f + __expf(-v));
          o[g] = f2b(v);
        }
        u32 p0 = (u32)o[0] | ((u32)o[1] << 16);
        u32 p1 = (u32)o[2] | ((u32)o[3] << 16);
        *(uint2*)(Op + (size_t)node*CDIM + ct*16 + quad*4) = make_uint2(p0, p1);
      }
    }
  }
}

// ---------------- per-layer: quad-per-edge gather + LDS redistribute + 2ch/lane epilogue ----------------
__global__ __launch_bounds__(256) void k_layer_epi(
  const u16* __restrict__ xw, const u16* __restrict__ h, const u16* __restrict__ xl,
  const int2* __restrict__ colw, const u32* __restrict__ rowstart, const float* __restrict__ dinv,
  const u16* __restrict__ bg, const u16* __restrict__ bng, const u16* __restrict__ bnb,
  const u16* __restrict__ bnrm, const u16* __restrict__ bnrv,
  const u16* __restrict__ lng, const u16* __restrict__ lnb,
  const u16* __restrict__ flng, const u16* __restrict__ flnb,
  float* __restrict__ xlocal, u16* __restrict__ xout, int n, int first, int final)
{
  __shared__ float redis[4][128];
  const int lane = threadIdx.x & 63;
  const int quad = lane >> 4;
  const int l16 = lane & 15;
  const int wv = threadIdx.x >> 6;
  int node = blockIdx.x*4 + wv;
  const int valid = (node < n);
  if(!valid) node = n - 1;
  const int cg = l16*8;
  u32 j0 = rowstart[node], j1 = rowstart[node+1];
  float a[8];
  #pragma unroll
  for(int g=0; g<8; g++) a[g] = 0.f;

  for(u32 base = j0; base < j1; base += 64){
    int avail = (int)(j1 - base);
    int cnt = avail < 64 ? avail : 64;
    int2 pw = make_int2(0, 0);              // pad: src 0 (valid row), w = +0.0f
    if(lane < cnt) pw = colw[base + lane];
    int cntp = (cnt + 15) & ~15;
    for(int t = 0; t < cntp; t += 16){
      int s[4]; float w[4]; ushort8v v[4];
      #pragma unroll
      for(int u=0; u<4; u++){
        s[u] = __shfl(pw.x, t + u*4 + quad, 64);
        w[u] = __int_as_float(__shfl(pw.y, t + u*4 + quad, 64));
      }
      #pragma unroll
      for(int u=0; u<4; u++) v[u] = *(const ushort8v*)(xw + (size_t)s[u]*CDIM + cg);
      #pragma unroll
      for(int u=0; u<4; u++){
        #pragma unroll
        for(int g=0; g<8; g++) a[g] = fmaf(w[u], b2f(v[u][g]), a[g]);
      }
    }
  }
  #pragma unroll
  for(int g=0; g<8; g++){
    a[g] += __shfl_xor(a[g], 16, 64);
    a[g] += __shfl_xor(a[g], 32, 64);
  }
  if(quad == 0){
    *(float4*)&redis[wv][cg]     = make_float4(a[0],a[1],a[2],a[3]);
    *(float4*)&redis[wv][cg + 4] = make_float4(a[4],a[5],a[6],a[7]);
  }
  __syncthreads();
  const int c0 = lane*2;
  float2 av = *(float2*)&redis[wv][c0];
  float a0 = av.x, a1 = av.y;

  float dn = dinv[node], sw = dn*dn;
  size_t base = (size_t)node*CDIM + c0;
  ushort2 xwv = *(const ushort2*)(xw + base);
  ushort2 xlv = *(const ushort2*)(xl + base);
  ushort2 hv  = *(const ushort2*)(h  + base);
  float x10 = a0*dn + b2f(xwv.x)*sw + b2f(bg[c0])   + b2f(xlv.x);
  float x11 = a1*dn + b2f(xwv.y)*sw + b2f(bg[c0+1]) + b2f(xlv.y);
  float s0 = rsqrtf(b2f(bnrv[c0])   + 1e-5f) * b2f(bng[c0]);
  float s1 = rsqrtf(b2f(bnrv[c0+1]) + 1e-5f) * b2f(bng[c0+1]);
  float x20 = (x10 - b2f(bnrm[c0]))*s0   + b2f(bnb[c0]);
  float x21 = (x11 - b2f(bnrm[c0+1]))*s1 + b2f(bnb[c0+1]);
  float x30 = fmaxf(x20, 0.f);
  float x31 = fmaxf(x21, 0.f);
  float t0 = b2f(hv.x)*x30, t1 = b2f(hv.y)*x31;
  float mu = wsum64(t0 + t1) * (1.f/128.f);
  float d0 = t0 - mu, d1 = t1 - mu;
  float var = wsum64(d0*d0 + d1*d1) * (1.f/128.f);
  float inv = rsqrtf(var + 1e-5f);
  float y0 = d0*inv*b2f(lng[c0])   + b2f(lnb[c0]);
  float y1 = d1*inv*b2f(lng[c0+1]) + b2f(lnb[c0+1]);
  float xn0 = 0.1f*y0 + 0.9f*x30;
  float xn1 = 0.1f*y1 + 0.9f*x31;
  float2 xl2;
  if(first){
    xl2.x = xn0; xl2.y = xn1;
  } else {
    xl2 = *(float2*)(xlocal + base);
    xl2.x += xn0; xl2.y += xn1;
  }
  if(!final){
    if(valid){
      *(float2*)(xlocal + base) = xl2;
      ushort2 o; o.x = f2b(xn0); o.y = f2b(xn1);
      *(ushort2*)(xout + base) = o;
    }
  } else {
    float mu2 = wsum64(xl2.x + xl2.y) * (1.f/128.f);
    float e0 = xl2.x - mu2, e1 = xl2.y - mu2;
    float var2 = wsum64(e0*e0 + e1*e1) * (1.f/128.f);
    float inv2 = rsqrtf(var2 + 1e-5f);
    if(valid){
      ushort2 o;
      o.x = f2b(e0*inv2*b2f(flng[c0])   + b2f(flnb[c0]));
      o.y = f2b(e1*inv2*b2f(flng[c0+1]) + b2f(flnb[c0+1]));
      *(ushort2*)(xout + base) = o;
    }
  }
}

// ---------------- kv = k^T v partials (+ k column sums) ----------------
__global__ __launch_bounds__(256) void k_kv(
  const u16* __restrict__ kk, const u16* __restrict__ vv, int n, int npb,
  float* __restrict__ part)
{
  __shared__ float sk[8][128];
  __shared__ float sv[8][128];
  const int tid = threadIdx.x;
  const int tr = tid >> 4, tc = tid & 15;
  float acc[8][8];
  #pragma unroll
  for(int i=0;i<8;i++){
    #pragma unroll
    for(int j=0;j<8;j++) acc[i][j] = 0.f;
  }
  float ks[8];
  #pragma unroll
  for(int i=0;i<8;i++) ks[i] = 0.f;
  int start = blockIdx.x * npb;
  int end = start + npb; if(end > n) end = n;
  const int lr = tid >> 5;
  const int lc = (tid & 31) * 4;
  for(int g0 = start; g0 < end; g0 += 8){
    int cnt = end - g0; if(cnt > 8) cnt = 8;
    __syncthreads();
    if(lr < cnt){
      ushort4 kq = *(const ushort4*)(kk + (size_t)(g0+lr)*CDIM + lc);
      ushort4 vq = *(const ushort4*)(vv + (size_t)(g0+lr)*CDIM + lc);
      sk[lr][lc] = b2f(kq.x); sk[lr][lc+1] = b2f(kq.y); sk[lr][lc+2] = b2f(kq.z); sk[lr][lc+3] = b2f(kq.w);
      sv[lr][lc] = b2f(vq.x); sv[lr][lc+1] = b2f(vq.y); sv[lr][lc+2] = b2f(vq.z); sv[lr][lc+3] = b2f(vq.w);
    }
    __syncthreads();
    for(int r=0; r<cnt; r++){
      float4 ka = *(const float4*)&sk[r][tr*8];
      float4 kb = *(const float4*)&sk[r][tr*8+4];
      float4 va = *(const float4*)&sv[r][tc*8];
      float4 vb = *(const float4*)&sv[r][tc*8+4];
      float kr[8] = {ka.x,ka.y,ka.z,ka.w,kb.x,kb.y,kb.z,kb.w};
      float vr[8] = {va.x,va.y,va.z,va.w,vb.x,vb.y,vb.z,vb.w};
      #pragma unroll
      for(int i=0;i<8;i++){
        #pragma unroll
        for(int j=0;j<8;j++) acc[i][j] = fmaf(kr[i], vr[j], acc[i][j]);
      }
      if(tc == 0){
        #pragma unroll
        for(int i=0;i<8;i++) ks[i] += kr[i];
      }
    }
  }
  float* p = part + (size_t)blockIdx.x * 16512;
  #pragma unroll
  for(int i=0;i<8;i++){
    #pragma unroll
    for(int j=0;j<8;j++)
      p[(size_t)(tc*8+j)*CDIM + tr*8 + i] = acc[i][j];
  }
  if(tc == 0){
    #pragma unroll
    for(int i=0;i<8;i++) p[16384 + tr*8 + i] = ks[i];
  }
}

// reduce partials -> Bext bf16 [144][128]
__global__ void k_kvred(const float* __restrict__ part, int nb, u16* __restrict__ Bext){
  int i = blockIdx.x*256 + threadIdx.x;
  if(i >= 144*128) return;
  float s = 0.f;
  if(i < 16512){
    #pragma unroll 8
    for(int b=0;b<nb;b++) s += part[(size_t)b*16512 + i];
  }
  Bext[i] = f2b(s);
}

// ---------------- fused attention tail: num GEMM + den + LN + x(h+0.9) + gWo GEMM + relu
//                  (+ final Wp projection when last) ----------------
__global__ __launch_bounds__(256) void k_attn(
  const u16* __restrict__ q, const u16* __restrict__ Bext, const u16* __restrict__ hg,
  const u16* __restrict__ g, const u16* __restrict__ b,
  const u16* __restrict__ Wo, const u16* __restrict__ bo,
  const u16* __restrict__ Wp, const u16* __restrict__ bp,
  u16* __restrict__ xgout, void* __restrict__ outv,
  int M, int last, const int* __restrict__ flags)
{
  __shared__ u16 stg[4][32*136];
  const int lane = threadIdx.x & 63;
  const int wv = threadIdx.x >> 6;
  const int l16 = lane & 15, quad = lane >> 4;
  const long rbase = (long)blockIdx.x*128 + wv*32;
  u16* st = stg[wv];

  // ---- stage 1: num/den GEMM + LN -> y staged in LDS ----
  {
    short8 af[2][4];
    #pragma unroll
    for(int rt=0; rt<2; rt++){
      long r = rbase + rt*16 + l16; if(r >= M) r = M-1;
      const u16* ap = q + r*CDIM + quad*8;
      #pragma unroll
      for(int kt=0; kt<4; kt++)
        af[rt][kt] = *(const short8*)(ap + kt*32);
    }
    f32x4 acc[2][9];
    f32x4 zero = {0.f,0.f,0.f,0.f};
    #pragma unroll
    for(int rt=0; rt<2; rt++){
      #pragma unroll
      for(int ct=0; ct<9; ct++) acc[rt][ct] = zero;
    }
    #pragma unroll
    for(int ct=0; ct<9; ct++){
      const u16* wp = Bext + (ct*16 + l16)*CDIM + quad*8;
      #pragma unroll
      for(int kt=0; kt<4; kt++){
        short8 bf = *(const short8*)(wp + kt*32);
        acc[0][ct] = __builtin_amdgcn_mfma_f32_16x16x32_bf16(af[0][kt], bf, acc[0][ct], 0, 0, 0);
        acc[1][ct] = __builtin_amdgcn_mfma_f32_16x16x32_bf16(af[1][kt], bf, acc[1][ct], 0, 0, 0);
      }
    }
    #pragma unroll
    for(int rt=0; rt<2; rt++){
      float rden[4];
      #pragma unroll
      for(int gi=0; gi<4; gi++){
        float dv = __shfl(acc[rt][8][gi], lane & 48, 64);
        rden[gi] = 1.f/(dv + 1e-6f);
      }
      #pragma unroll
      for(int gi=0; gi<4; gi++){
        float sum = 0.f;
        #pragma unroll
        for(int ct=0; ct<8; ct++) sum += acc[rt][ct][gi]*rden[gi];
        float mu = wsum16(sum) * (1.f/128.f);
        float vs = 0.f;
        #pragma unroll
        for(int ct=0; ct<8; ct++){ float d = acc[rt][ct][gi]*rden[gi] - mu; vs = fmaf(d, d, vs); }
        float inv = rsqrtf(wsum16(vs)*(1.f/128.f) + 1e-5f);
        const int rowl = rt*16 + quad*4 + gi;
        #pragma unroll
        for(int ct=0; ct<8; ct++){
          int col = ct*16 + l16;
          float y = (acc[rt][ct][gi]*rden[gi] - mu)*inv*b2f(g[col]) + b2f(b[col]);
          st[rowl*136 + col] = f2b(y);
        }
      }
    }
  }
  // ---- stage 2: y *= (h + 0.9), coalesced hg reads, in-place in LDS ----
  #pragma unroll
  for(int p2=0; p2<8; p2++){
    int row = (p2>>2)*16 + (lane>>2);
    int seg = (lane&3) + (p2&3)*4;
    long node = rbase + row;
    if(node >= M) node = M-1;
    ushort8v yv = *(const ushort8v*)&st[row*136 + seg*8];
    ushort8v hv = *(const ushort8v*)(hg + (size_t)node*CDIM + seg*8);
    ushort8v o;
    #pragma unroll
    for(int i2=0; i2<8; i2++)
      o[i2] = f2b(b2f(yv[i2]) * (b2f(hv[i2]) + 0.9f));
    *(ushort8v*)&st[row*136 + seg*8] = o;
  }
  // ---- stage 3: p-fragments from LDS (B-operand layout) ----
  short8 pf[2][4];
  #pragma unroll
  for(int nt=0; nt<2; nt++){
    #pragma unroll
    for(int kt=0; kt<4; kt++)
      pf[nt][kt] = *(const short8*)&st[(nt*16 + l16)*136 + quad*8 + kt*32];
  }
  // ---- stage 4: out2 = relu(p @ Wo^T + bo), restaged into LDS ----
  #pragma unroll
  for(int ct=0; ct<8; ct++){
    f32x4 a0 = {0.f,0.f,0.f,0.f}, a1 = {0.f,0.f,0.f,0.f};
    const u16* wp = Wo + (ct*16 + l16)*CDIM + quad*8;
    #pragma unroll
    for(int kt=0; kt<4; kt++){
      short8 wf = *(const short8*)(wp + kt*32);
      a0 = __builtin_amdgcn_mfma_f32_16x16x32_bf16(wf, pf[0][kt], a0, 0, 0, 0);
      a1 = __builtin_amdgcn_mfma_f32_16x16x32_bf16(wf, pf[1][kt], a1, 0, 0, 0);
    }
    ushort4 bq = *(const ushort4*)(bo + ct*16 + quad*4);
    float bv[4] = {b2f(bq.x), b2f(bq.y), b2f(bq.z), b2f(bq.w)};
    #pragma unroll
    for(int nt=0; nt<2; nt++){
      f32x4 a = nt ? a1 : a0;
      u16 o[4];
      #pragma unroll
      for(int g2=0; g2<4; g2++)
        o[g2] = f2b(fmaxf(a[g2] + bv[g2], 0.f));
      u32 p0 = (u32)o[0] | ((u32)o[1] << 16);
      u32 p1 = (u32)o[2] | ((u32)o[3] << 16);
      *(uint2*)&st[(nt*16 + l16)*136 + ct*16 + quad*4] = make_uint2(p0, p1);
    }
  }
  if(!last){
    // ---- stage 5a: coalesced copy-out to xg ----
    #pragma unroll
    for(int p2=0; p2<8; p2++){
      int row = (p2>>2)*16 + (lane>>2);
      int seg = (lane&3) + (p2&3)*4;
      long node = rbase + row;
      ushort8v v = *(const ushort8v*)&st[row*136 + seg*8];
      if(node < M)
        *(ushort8v*)(xgout + (size_t)node*CDIM + seg*8) = v;
    }
  } else {
    // ---- stage 5b: final projection out = p2 @ Wp^T + bp (40 cols) ----
    const int f32m = flags[0];
    short8 pf2[2][4];
    #pragma unroll
    for(int nt=0; nt<2; nt++){
      #pragma unroll
      for(int kt=0; kt<4; kt++)
        pf2[nt][kt] = *(const short8*)&st[(nt*16 + l16)*136 + quad*8 + kt*32];
    }
    #pragma unroll
    for(int ct=0; ct<3; ct++){
      f32x4 a0 = {0.f,0.f,0.f,0.f}, a1 = {0.f,0.f,0.f,0.f};
      int wrow = ct*16 + l16; if(wrow > 39) wrow = 39;
      const u16* wp = Wp + wrow*CDIM + quad*8;
      #pragma unroll
      for(int kt=0; kt<4; kt++){
        short8 wf = *(const short8*)(wp + kt*32);
        a0 = __builtin_amdgcn_mfma_f32_16x16x32_bf16(wf, pf2[0][kt], a0, 0, 0, 0);
        a1 = __builtin_amdgcn_mfma_f32_16x16x32_bf16(wf, pf2[1][kt], a1, 0, 0, 0);
      }
      const int ch0 = ct*16 + quad*4;
      if(ch0 < 40){
        ushort4 bq = *(const ushort4*)(bp + ch0);
        float bv[4] = {b2f(bq.x), b2f(bq.y), b2f(bq.z), b2f(bq.w)};
        #pragma unroll
        for(int nt=0; nt<2; nt++){
          long node = rbase + nt*16 + l16;
          if(node < M){
            f32x4 a = nt ? a1 : a0;
            if(f32m){
              float* op = (float*)outv + node*40 + ch0;
              #pragma unroll
              for(int g2=0; g2<4; g2++) op[g2] = a[g2] + bv[g2];
            } else {
              u16 o[4];
              #pragma unroll
              for(int g2=0; g2<4; g2++) o[g2] = f2b(a[g2] + bv[g2]);
              u32 p0 = (u32)o[0] | ((u32)o[1] << 16);
              u32 p1 = (u32)o[2] | ((u32)o[3] << 16);
              *(uint2*)((u16*)outv + node*40 + ch0) = make_uint2(p0, p1);
            }
          }
        }
      }
    }
  }
}

extern "C" void kernel_launch(void* const* d_in, const int* in_sizes, int n_in,
                              void* d_out, int out_size, void* d_ws, size_t ws_size,
                              hipStream_t stream)
{
  (void)n_in;
  const int C = CDIM;
  const int Nn = in_sizes[0] / C;
  const int E  = in_sizes[1] / 2;

  char* ws = (char*)d_ws;
  size_t off = 0;
  auto alloc = [&](size_t bytes) -> char* {
    char* p = ws + off;
    off = (off + bytes + 255) & ~(size_t)255;
    return p;
  };
  u16*   x_cur  = (u16*)  alloc((size_t)Nn*C*2);     // also xg after final epi
  float* xlocal = (float*)alloc((size_t)Nn*C*4);     // early: [xb bf16 | eib]; then accum; then kvpart
  u16*   hb     = (u16*)  alloc((size_t)Nn*C*2);
  u16*   xwb    = (u16*)  alloc((size_t)Nn*C*2);
  u16*   xlb    = (u16*)  alloc((size_t)Nn*C*2);
  float* dinv   = (float*)alloc((size_t)Nn*4);
  u32*   cnt    = (u32*)  alloc((size_t)Nn*4);
  u32*   rowst  = (u32*)  alloc((size_t)(Nn+1)*4);
  u32*   cursor = (u32*)  alloc((size_t)Nn*4);
  int2*  colw   = (int2*) alloc((size_t)E*8);
  u16*   Bext   = (u16*)  alloc((size_t)144*128*2);
  int*   flags  = (int*)  alloc(256);
  u32*   bsum   = (u32*)  alloc(1024*4);
  u32*   bpre   = (u32*)  alloc(1024*4);
  size_t ptot = 0;
  for(int k=2;k<26;k++) ptot += (size_t)in_sizes[k];
  u16* pbuf = (u16*)alloc(ptot*2);

  if(off > ws_size){
    hipMemsetAsync(d_out, 0, (size_t)out_size*2, stream);
    return;
  }

  const u16* pp[26];
  {
    size_t po = 0;
    for(int k=2;k<26;k++){ pp[k] = pbuf + po; po += (size_t)in_sizes[k]; }
  }
  const u16* cWh  = pp[2];  const u16* cbh  = pp[3];
  const u16* cWg  = pp[4];  const u16* cbg  = pp[5];
  const u16* cWl  = pp[6];  const u16* cbl  = pp[7];
  const u16* clng = pp[8];  const u16* clnb = pp[9];
  const u16* cbng = pp[10]; const u16* cbnb = pp[11];
  const u16* cbnrm= pp[12]; const u16* cbnrv= pp[13];
  const u16* cgWh = pp[14]; const u16* cgbh = pp[15];
  const u16* cgWk = pp[16]; const u16* cgWv = pp[17];
  const u16* cglng= pp[18]; const u16* cglnb= pp[19];
  const u16* cgWo = pp[20]; const u16* cgbo = pp[21];
  const u16* cflng= pp[22]; const u16* cflnb= pp[23];
  const u16* cWp  = pp[24]; const u16* cbp  = pp[25];

  u16* xb  = (u16*)xlocal;                             // dead after first k_gemm3
  int* eib = (int*)((char*)xlocal + (size_t)Nn*C*2);   // dead after k_scatter8
  u16* xg  = x_cur;
  float* kvpart = xlocal;                              // 512*16512*4 = 33.8MB <= Nn*C*4

  const int NB_KV = 512;
  const int npb = (Nn + NB_KV - 1) / NB_KV;
  const int gblk = (Nn + 127) / 128;
  const int gblk2 = (Nn + 255) / 256;
  const int nodeblk = (Nn + 3) / 4;
  const int nscan = (Nn + 255) / 256;     // 391 for N=100k (must be <= 1024)
  const int NSL = 512;

  k_probe<<<1, 256, 0, stream>>>((const u32*)d_in[0], (const u32*)d_in[1], flags);
  hipMemsetAsync(cnt, 0, (size_t)Nn*4, stream);
  k_cvt_ei_count<<<(2*E + 255)/256, 256, 0, stream>>>((const int*)d_in[1], eib, E, flags, cnt);
  k_cvt_x<<<(Nn*C/8 + 255)/256, 256, 0, stream>>>(d_in[0], xb, Nn*C, flags);
  {
    CvtArgs a;
    int maxn = 0;
    for(int k=2;k<26;k++){
      a.src[k-2] = d_in[k];
      a.dst[k-2] = (u16*)pp[k];
      a.n[k-2]   = in_sizes[k];
      if(in_sizes[k] > maxn) maxn = in_sizes[k];
    }
    dim3 g((maxn + 255)/256, 24);
    k_cvt_params<<<g, 256, 0, stream>>>(a, flags);
  }

  k_scan1<<<nscan, 256, 0, stream>>>(cnt, Nn, bsum);
  k_scan2<<<1, 1024, 0, stream>>>(bsum, nscan, bpre);
  k_scan3<<<nscan, 256, 0, stream>>>(cnt, Nn, bpre, rowst, cursor, dinv);
  k_scatter8<<<NSL*8, 256, 0, stream>>>(eib, E, Nn, NSL, cursor, dinv, colw);

  const u16* xa = xb;
  for(int i=0; i<7; i++){
    k_gemm3<<<dim3(gblk2,3), 256, 0, stream>>>(xa, Nn,
        cWh + (size_t)i*C*C, cbh + (size_t)i*C, 1, hb,
        cWg + (size_t)i*C*C, (const u16*)nullptr, 0, xwb,
        cWl + (size_t)i*C*C, cbl + (size_t)i*C, 0, xlb);
    k_layer_epi<<<nodeblk, 256, 0, stream>>>(xwb, hb, xlb, colw, rowst, dinv,
        cbg + (size_t)i*C, cbng + (size_t)i*C, cbnb + (size_t)i*C,
        cbnrm + (size_t)i*C, cbnrv + (size_t)i*C,
        clng + (size_t)i*C, clnb + (size_t)i*C,
        cflng, cflnb,
        xlocal, x_cur, Nn, (i==0) ? 1 : 0, (i==6) ? 1 : 0);
    xa = x_cur;
  }

  for(int j=0; j<2; j++){
    k_gemm3<<<dim3(gblk2,3), 256, 0, stream>>>(xg, Nn,
        cgWh + (size_t)j*C*C, cgbh + (size_t)j*C, 0, hb,
        cgWk + (size_t)j*C*C, (const u16*)nullptr, 2, xwb,
        cgWv + (size_t)j*C*C, (const u16*)nullptr, 0, xlb);
    k_kv   <<<NB_KV, 256, 0, stream>>>(xwb, xlb, Nn, npb, kvpart);
    k_kvred<<<(144*128 + 255)/256, 256, 0, stream>>>(kvpart, NB_KV, Bext);
    k_attn <<<gblk, 256, 0, stream>>>(xwb, Bext, hb,
        cglng + (size_t)j*C, cglnb + (size_t)j*C,
        cgWo + (size_t)j*C*C, cgbo + (size_t)j*C,
        cWp, cbp, xg, d_out, Nn, (j==1) ? 1 : 0, flags);
  }
}